// Round 10
// baseline (19977.162 us; speedup 1.0000x reference)
//
#include <hip/hip_runtime.h>
#include <hip/hip_bf16.h>

// Problem constants
#define E_   256
#define H_   512
#define T_   512
#define B_   128
#define TBE_ (T_*B_*E_)

#define GW 32               // gate WGs per branch (one full XCD)
#define YW 8                // y WGs per branch (anywhere else)
#define RROT 4              // local state rotation
#define RROTM 8             // MALL h1 copy rotation (y lag cushion)
#define LDS_BYTES 122880    // 73728 (stage-A frags) + 49152 (stage-B frags)

typedef __attribute__((ext_vector_type(4))) float  f32x4;
typedef __attribute__((ext_vector_type(8))) __bf16 bf16x8;
typedef __attribute__((ext_vector_type(8))) short  short8;
typedef __attribute__((ext_vector_type(4))) unsigned int u32x4;

// ---- workspace layout (bytes) ----
#define OFF_LF0  0          // branch0 local flags: 32 x 64B
#define OFF_LF1  2048       // branch1 local flags
#define OFF_MF0  4096       // branch0 MALL flags: 32 x 64B
#define OFF_MF1  6144       // branch1 MALL flags
#define OFF_TICK 8192       // 4 ticket counters (16B)
#define OFF_WA   12288                         // stage-A frag weights [2][32][3][24][64][8] bf16
#define SZ_WA    (2*GW*3*24*64*8*2)            // 4,718,592
#define OFF_WY   (OFF_WA + SZ_WA)              // y frag weights
#define SZ_WY    (YW*2*16*64*8*2)              // 262,144
#define OFF_WB   (OFF_WY + SZ_WY)              // stage-B frag weights
#define SZ_WB    (2*GW*3*16*64*8*2)            // 3,145,728
#define OFF_BA0  (OFF_WB + SZ_WB)
#define OFF_BA1  (OFF_BA0 + 2*1536*4)
#define OFF_BBv  (OFF_BA1 + 2*1536*4)
#define OFF_XA   (OFF_BBv + 2*1536*4)          // local h1 [RROT][2][16][128][32] bf16
#define SZ_XL    (RROT*2*B_*H_*2)              // 1,048,576
#define OFF_XB   (OFF_XA + SZ_XL)              // local h0, same layout
#define OFF_XAM  (OFF_XB + SZ_XL)              // MALL h1 copy [RROTM][2][...]
#define SZ_XAM   (RROTM*2*B_*H_*2)             // 2,097,152
#define WS_NEED  (OFF_XAM + SZ_XAM)            // ~12.4 MB

__device__ __host__ inline int gate_src_row(int p) {
  // packed row p in [0,1536): w=p/48 slice, r=p%48: [0,16)=i, [16,32)=g, [32,48)=o
  int w = p / 48, r = p % 48;
  int grp = r >> 4;
  int idx = r & 15;
  int base = (grp == 0) ? 0 : (grp == 1 ? 1024 : 1536);
  return base + 16*w + idx;
}

__device__ inline unsigned short f2bf(float f) {   // RNE f32->bf16
  unsigned u = __float_as_uint(f);
  u += 0x7fffu + ((u >> 16) & 1u);
  return (unsigned short)(u >> 16);
}
__device__ inline float sigf(float x)      { return __builtin_amdgcn_rcpf(1.f + __expf(-x)); }
__device__ inline float tanh_fast(float x) { return 1.f - 2.f*__builtin_amdgcn_rcpf(1.f + __expf(2.f*x)); }

__device__ inline unsigned pk2(float a, float b) {   // v_cvt_pk_bf16_f32 (RNE)
  unsigned r;
  asm("v_cvt_pk_bf16_f32 %0, %1, %2" : "=v"(r) : "v"(a), "v"(b));
  return r;
}

// MALL push (y-path only): r3/r5/r8-proven compiler atomic exchange (executes
// at the MALL). Issued lazily; drained by the NEXT step's vmcnt(0).
__device__ inline void st_mall_u64(unsigned short* p, unsigned long long v) {
  (void)__hip_atomic_exchange((unsigned long long*)p, v, __ATOMIC_RELAXED, __HIP_MEMORY_SCOPE_AGENT);
}

// ---- XCD-local barrier (the round-10 thesis) ----
// Same-XCD CUs share one L2. Plain stores land dirty in it; agent-ACQUIRE fence
// invalidates L1 (+clean L2 lines only -> local dirty state survives); plain
// loads then read the shared L2. No MALL round-trips on the recurrence path.
__device__ inline unsigned get_xcc() {
  unsigned x;
  asm volatile("s_getreg_b32 %0, hwreg(HW_REG_XCC_ID)" : "=s"(x));
  return x;
}
__device__ inline void lbar_arrive(unsigned* lfl, int w, unsigned phase) {
  asm volatile("s_waitcnt vmcnt(0)" ::: "memory");   // data stores L2-visible first
  __syncthreads();
  if (threadIdx.x == 0) {
    __builtin_amdgcn_sched_barrier(0);
    *(volatile unsigned*)(lfl + (size_t)w*16) = phase;
  }
}
__device__ inline void lbar_arrive_m(unsigned* lfl, unsigned* mfl, int w, unsigned phase, unsigned mval) {
  asm volatile("s_waitcnt vmcnt(0)" ::: "memory");   // also drains prior MALL pushes
  __syncthreads();
  if (threadIdx.x == 0) {
    __builtin_amdgcn_sched_barrier(0);
    *(volatile unsigned*)(lfl + (size_t)w*16) = phase;
    (void)__hip_atomic_exchange(mfl + (size_t)w*16, mval, __ATOMIC_RELAXED, __HIP_MEMORY_SCOPE_AGENT);
  }
}
__device__ inline void lbar_wait(unsigned* lfl, unsigned phase) {
  if (threadIdx.x < 64) {
    const volatile unsigned* p = lfl + (size_t)(threadIdx.x & 31)*16;
    for (;;) {
      __builtin_amdgcn_fence(__ATOMIC_ACQUIRE, "agent");   // inv L1, refetch L2
      unsigned v = *p;
      if (__all(v >= phase)) break;
      __builtin_amdgcn_s_sleep(0);
    }
  }
  __syncthreads();
  __builtin_amdgcn_fence(__ATOMIC_ACQUIRE, "agent");       // all waves: L1 inv before data loads
  __builtin_amdgcn_sched_barrier(0);
}

// y-side MALL flag poll (r5-proven sc0sc1 pattern; monotonic -> stale just spins)
__device__ inline unsigned mall_poll(const unsigned* p) {
  unsigned v;
  asm volatile("global_load_dword %0, %1, off sc0 sc1\n\ts_waitcnt vmcnt(0)"
               : "=&v"(v) : "v"(p) : "memory");
  return v;
}
__device__ inline void ybar_wait(unsigned* mfl, unsigned need) {
  if (threadIdx.x < 64) {
    unsigned* p = mfl + (size_t)(threadIdx.x & 31)*16;
    int spins = 0;
    for (;;) {
      unsigned v = mall_poll(p);
      if (__all(v >= need)) break;
      if (((++spins) & 255) == 255) {
        unsigned a = __hip_atomic_fetch_add(p, 0u, __ATOMIC_RELAXED, __HIP_MEMORY_SCOPE_AGENT);
        if (__all(a >= need)) break;
      }
    }
  }
  __syncthreads();
  __builtin_amdgcn_fence(__ATOMIC_ACQUIRE, "agent");   // drop clean xAm lines -> fresh MALL reads
  __builtin_amdgcn_sched_barrier(0);
}

// ======================= weight packing (fragment order) =======================
// frag elem index within a WG slice: ((mt*KT + kt)*64 + lane)*8 + e
// lane = lg*16 + ln holds row (mt*16+ln), k = kt*32 + lg*8 + e

__global__ __launch_bounds__(256) void k_pack_wc(const float* __restrict__ uW0, const float* __restrict__ lW0,
                                                 const float* __restrict__ linW, unsigned short* __restrict__ WAf) {
  int blk = blockIdx.x;                 // 2*1536 blocks
  int branch = blk / 1536, p = blk % 1536;
  const float* W0 = branch ? lW0 : uW0;
  int s = gate_src_row(p);
  int w = p / 48, rr = p % 48, mt = rr >> 4, ln = rr & 15;
  __shared__ float a[256];
  int tid = threadIdx.x;
  a[tid] = W0[(size_t)s*512 + tid];     // W0p row (cols 0:256 = prev-embed part)
  __syncthreads();
  size_t baseA = (((size_t)(branch*GW + w)*3 + mt)*24) * 64 * 8;
  for (int kk = 0; kk < 2; ++kk) {
    int k = kk*256 + tid;
    float acc = 0.f;
    #pragma unroll 8
    for (int e = 0; e < 256; ++e) acc = fmaf(a[e], linW[(size_t)e*512 + k], acc);
    int kt = k >> 5, lg = (k >> 3) & 3, e = k & 7;
    WAf[baseA + ((size_t)kt*64 + lg*16 + ln)*8 + e] = f2bf(acc);
  }
}

__global__ __launch_bounds__(256) void k_pack_rest(
    const float* __restrict__ uW0, const float* __restrict__ ubi0, const float* __restrict__ ubh0,
    const float* __restrict__ uW1, const float* __restrict__ ubi1, const float* __restrict__ ubh1,
    const float* __restrict__ lW0, const float* __restrict__ lbi0, const float* __restrict__ lbh0,
    const float* __restrict__ lW1, const float* __restrict__ lbi1, const float* __restrict__ lbh1,
    const float* __restrict__ linb,
    unsigned short* __restrict__ WAf, unsigned short* __restrict__ WBf,
    float* __restrict__ bA0, float* __restrict__ bA1, float* __restrict__ bBv) {
  int blk = blockIdx.x;
  int branch = blk / 1536, p = blk % 1536;
  const float* W0  = branch ? lW0  : uW0;
  const float* bi0 = branch ? lbi0 : ubi0;
  const float* bh0 = branch ? lbh0 : ubh0;
  const float* W1  = branch ? lW1  : uW1;
  const float* bi1 = branch ? lbi1 : ubi1;
  const float* bh1 = branch ? lbh1 : ubh1;
  int s = gate_src_row(p);
  int w = p / 48, rr = p % 48, mt = rr >> 4, ln = rr & 15;
  int tid = threadIdx.x;
  size_t baseA = (((size_t)(branch*GW + w)*3 + mt)*24) * 64 * 8;
  size_t baseB = (((size_t)(branch*GW + w)*3 + mt)*16) * 64 * 8;
  {  // W0f (feat part) -> kt 16..23
    int c = tid;
    int kt = 16 + (c >> 5), lg = (c >> 3) & 3, e = c & 7;
    WAf[baseA + ((size_t)kt*64 + lg*16 + ln)*8 + e] = f2bf(W0[(size_t)s*512 + 256 + c]);
  }
  for (int half = 0; half < 2; ++half) {
    int k = half*256 + tid;
    int kt = k >> 5, lg = (k >> 3) & 3, e = k & 7;
    WBf[baseB + ((size_t)kt*64 + lg*16 + ln)*8 + e] = f2bf(W1[(size_t)s*512 + k]);
  }
  __shared__ float red[256];
  red[tid] = W0[(size_t)s*512 + tid] * linb[tid];   // c0 = W0p @ lin_b
  __syncthreads();
  for (int st = 128; st > 0; st >>= 1) { if (tid < st) red[tid] += red[tid + st]; __syncthreads(); }
  if (tid == 0) {
    size_t rowA = (size_t)branch*1536 + p;
    float b0 = bi0[s] + bh0[s];
    bA0[rowA] = b0;
    bA1[rowA] = b0 + red[0];
    bBv[rowA] = bi1[s] + bh1[s];
  }
}

__global__ __launch_bounds__(256) void k_pack_wy(const float* __restrict__ linW, unsigned short* __restrict__ WYf) {
  int row = blockIdx.x;                 // 256 blocks
  int w2 = row >> 5, rr = row & 31, mt = rr >> 4, ln = rr & 15;
  int tid = threadIdx.x;
  size_t base = ((size_t)(w2*2 + mt)*16) * 64 * 8;
  for (int half = 0; half < 2; ++half) {
    int k = half*256 + tid;
    int kt = k >> 5, lg = (k >> 3) & 3, e = k & 7;
    WYf[base + ((size_t)kt*64 + lg*16 + ln)*8 + e] = f2bf(linW[(size_t)row*512 + k]);
  }
}

// ======================= persistent recurrent kernel =======================

__global__ __launch_bounds__(256, 1) void k_rnn(
    const float* __restrict__ featU, const float* __restrict__ featL,
    const float* __restrict__ linb,
    float* __restrict__ out, unsigned char* __restrict__ ws) {

  extern __shared__ unsigned char lds[];
  __shared__ int sRole;

  const int tid = threadIdx.x;
  // ---- mapping-independent role assignment: ticket per ACTUAL XCD ----
  if (tid == 0) {
    unsigned xcc = get_xcc();
    int enc = -1;
    unsigned* tick = (unsigned*)(ws + OFF_TICK);
    if (xcc < 2) {      // gate XCDs: branch = xcc
      unsigned r = __hip_atomic_fetch_add(&tick[xcc], 1u, __ATOMIC_RELAXED, __HIP_MEMORY_SCOPE_AGENT);
      if (r < GW) enc = (int)(xcc*64 + r);
    } else {            // y pool: first 16 tickets -> 8 per branch
      unsigned r = __hip_atomic_fetch_add(&tick[2], 1u, __ATOMIC_RELAXED, __HIP_MEMORY_SCOPE_AGENT);
      if (r < 2*YW) enc = (int)((r >> 3)*64 + 32 + (r & 7));
    }
    sRole = enc;
  }
  __syncthreads();
  const int enc = sRole;
  if (enc < 0) return;
  const int branch = enc >> 6;
  const int role   = enc & 63;
  const bool isGate = role < 32;
  const int w = isGate ? role : (role - 32);
  const float* feat = branch ? featL : featU;

  const unsigned short* WAf = (const unsigned short*)(ws + OFF_WA);
  const unsigned short* WYf = (const unsigned short*)(ws + OFF_WY);
  const unsigned short* WBf = (const unsigned short*)(ws + OFF_WB);
  const float* bA0 = (const float*)(ws + OFF_BA0) + branch*1536;
  const float* bA1 = (const float*)(ws + OFF_BA1) + branch*1536;
  const float* bBv = (const float*)(ws + OFF_BBv) + branch*1536;
  unsigned short* xAr  = (unsigned short*)(ws + OFF_XA);    // local h1 slots
  unsigned short* xBr  = (unsigned short*)(ws + OFF_XB);    // local h0 slots
  unsigned short* xAmr = (unsigned short*)(ws + OFF_XAM);   // MALL h1 slots
  unsigned* lfl = (unsigned*)(ws + (branch ? OFF_LF1 : OFF_LF0));
  unsigned* mfl = (unsigned*)(ws + (branch ? OFF_MF1 : OFF_MF0));

  const int l   = tid & 63;
  const int wv  = tid >> 6;   // wave 0..3
  const int lg  = l >> 4;     // k-subgroup 0..3
  const int ln  = l & 15;     // row/col in tile

  // ---- stage weights into LDS ----
  if (isGate) {
    const uint4* srcA = (const uint4*)(WAf + (size_t)(branch*GW + w)*36864);
    uint4* dA = (uint4*)lds;
    for (int i = tid; i < 4608; i += 256) dA[i] = srcA[i];
    const uint4* srcB = (const uint4*)(WBf + (size_t)(branch*GW + w)*24576);
    uint4* dB = (uint4*)(lds + 73728);
    for (int i = tid; i < 3072; i += 256) dB[i] = srcB[i];
  } else {
    const uint4* srcY = (const uint4*)(WYf + (size_t)w*16384);
    uint4* dY = (uint4*)lds;
    for (int i = tid; i < 2048; i += 256) dY[i] = srcY[i];
  }

  // ---- per-lane bias preload ----
  float ba0[12], ba1[12], bbv[12], by[8];
  if (isGate) {
    #pragma unroll
    for (int mt = 0; mt < 3; ++mt)
      #pragma unroll
      for (int rg = 0; rg < 4; ++rg) {
        int p = 48*w + mt*16 + 4*lg + rg;
        ba0[mt*4+rg] = bA0[p];
        ba1[mt*4+rg] = bA1[p];
        bbv[mt*4+rg] = bBv[p];
      }
  } else {
    #pragma unroll
    for (int mt = 0; mt < 2; ++mt)
      #pragma unroll
      for (int rg = 0; rg < 4; ++rg)
        by[mt*4+rg] = linb[32*w + mt*16 + 4*lg + rg];
  }
  __syncthreads();

  const f32x4 zv = {0.f, 0.f, 0.f, 0.f};

  if (isGate) {
    // featN: pre-accumulated feat-part of stage A for the NEXT timestep
    f32x4 featN[3][2];
    #pragma unroll
    for (int mt = 0; mt < 3; ++mt) { featN[mt][0] = zv; featN[mt][1] = zv; }

    auto featPart = [&](int lo, int hi, int tt) {
      for (int kt2 = lo; kt2 < hi; ++kt2) {
        short8 bfr[2];
        #pragma unroll
        for (int nt = 0; nt < 2; ++nt) {
          const int n = (wv*2 + nt)*16 + ln;
          const float* pf = feat + ((size_t)n*T_ + tt)*E_ + kt2*32 + 8*lg;
          float4 f0 = *(const float4*)pf;
          float4 f1 = *(const float4*)(pf + 4);
          u32x4 pk;
          pk.x = pk2(f0.x, f0.y); pk.y = pk2(f0.z, f0.w);
          pk.z = pk2(f1.x, f1.y); pk.w = pk2(f1.z, f1.w);
          bfr[nt] = __builtin_bit_cast(short8, pk);
        }
        #pragma unroll
        for (int mt = 0; mt < 3; ++mt) {
          short8 afr = *(const short8*)(lds + ((mt*24 + 16 + kt2)*64 + l)*16);
          #pragma unroll
          for (int nt = 0; nt < 2; ++nt)
            featN[mt][nt] = __builtin_amdgcn_mfma_f32_16x16x32_bf16(
                __builtin_bit_cast(bf16x8, afr), __builtin_bit_cast(bf16x8, bfr[nt]),
                featN[mt][nt], 0, 0, 0);
        }
      }
    };

    featPart(0, 8, 0);

    for (int t = 0; t < T_; ++t) {
      const unsigned short* xA_rd = xAr + ((size_t)((t-1) & (RROT-1))*2 + branch)*B_*H_;
      unsigned short*       xB_wr = xBr + ((size_t)(t & (RROT-1))*2 + branch)*B_*H_;
      const unsigned short* xB_rd = xB_wr;
      unsigned short*       xA_wr = xAr + ((size_t)(t & (RROT-1))*2 + branch)*B_*H_;
      unsigned short*       xAm_wr = xAmr + ((size_t)(t & (RROTM-1))*2 + branch)*B_*H_;

      // ---------------- stage A: h0(t) = act(Wc@h1(t-1) + featN + bias) ----------------
      f32x4 acc[3][2];
      #pragma unroll
      for (int mt = 0; mt < 3; ++mt)
        #pragma unroll
        for (int nt = 0; nt < 2; ++nt) { acc[mt][nt] = featN[mt][nt]; featN[mt][nt] = zv; }

      if (t > 0) {
        lbar_wait(lfl, 2u*t);                // h1(t-1) in local L2
        uint4 bs[2][16];                     // plain loads from shared local L2
        #pragma unroll
        for (int nt = 0; nt < 2; ++nt) {
          const int n = (wv*2 + nt)*16 + ln;
          const unsigned short* base = xA_rd + (size_t)n*32 + lg*8;
          #pragma unroll
          for (int kt = 0; kt < 16; ++kt)
            bs[nt][kt] = *(const uint4*)(base + (size_t)kt*4096);
        }
        #pragma unroll
        for (int kt = 0; kt < 16; ++kt) {
          #pragma unroll
          for (int mt = 0; mt < 3; ++mt) {
            short8 afr = *(const short8*)(lds + ((mt*24 + kt)*64 + l)*16);
            #pragma unroll
            for (int nt = 0; nt < 2; ++nt)
              acc[mt][nt] = __builtin_amdgcn_mfma_f32_16x16x32_bf16(
                  __builtin_bit_cast(bf16x8, afr),
                  __builtin_bit_cast(bf16x8, __builtin_bit_cast(u32x4, bs[nt][kt])),
                  acc[mt][nt], 0, 0, 0);
          }
        }
      }
      {
        float bcur[12];
        #pragma unroll
        for (int q = 0; q < 12; ++q) bcur[q] = (t == 0) ? ba0[q] : ba1[q];
        #pragma unroll
        for (int nt = 0; nt < 2; ++nt) {
          const int bcol = (wv*2 + nt)*16 + ln;
          unsigned long long hp[4];
          #pragma unroll
          for (int rg = 0; rg < 4; ++rg) {
            float iv = acc[0][nt][rg] + bcur[rg];
            float gv = acc[1][nt][rg] + bcur[4+rg];
            float ov = acc[2][nt][rg] + bcur[8+rg];
            float c  = sigf(iv) * tanh_fast(gv);
            float h  = sigf(ov) * tanh_fast(c);
            hp[rg] = (unsigned long long)f2bf(h);
          }
          unsigned long long v = hp[0] | (hp[1] << 16) | (hp[2] << 32) | (hp[3] << 48);
          *(unsigned long long*)(xB_wr + ((size_t)(w >> 1)*128 + bcol)*32 + (w & 1)*16 + lg*4) = v;
        }
      }
      // vmcnt(0) drains h0 stores AND step-(t-1) MALL pushes -> mflag=t is safe
      lbar_arrive_m(lfl, mfl, w, 2u*t + 1, (unsigned)t);
      if (t + 1 < T_) featPart(0, 4, t + 1);
      lbar_wait(lfl, 2u*t + 1);              // h0(t) in local L2

      // ---------------- stage B: h1(t) = act(W1@h0(t) + bias) ----------------
      unsigned long long pv[2]; size_t poff[2];
      {
        uint4 cs[2][16];
        #pragma unroll
        for (int nt = 0; nt < 2; ++nt) {
          const int n = (wv*2 + nt)*16 + ln;
          const unsigned short* base = xB_rd + (size_t)n*32 + lg*8;
          #pragma unroll
          for (int kt = 0; kt < 16; ++kt)
            cs[nt][kt] = *(const uint4*)(base + (size_t)kt*4096);
        }
        f32x4 accB[3][2];
        #pragma unroll
        for (int mt = 0; mt < 3; ++mt) { accB[mt][0] = zv; accB[mt][1] = zv; }
        #pragma unroll
        for (int kt = 0; kt < 16; ++kt) {
          #pragma unroll
          for (int mt = 0; mt < 3; ++mt) {
            short8 afr = *(const short8*)(lds + 73728 + ((mt*16 + kt)*64 + l)*16);
            #pragma unroll
            for (int nt = 0; nt < 2; ++nt)
              accB[mt][nt] = __builtin_amdgcn_mfma_f32_16x16x32_bf16(
                  __builtin_bit_cast(bf16x8, afr),
                  __builtin_bit_cast(bf16x8, __builtin_bit_cast(u32x4, cs[nt][kt])),
                  accB[mt][nt], 0, 0, 0);
          }
        }
        #pragma unroll
        for (int nt = 0; nt < 2; ++nt) {
          const int bcol = (wv*2 + nt)*16 + ln;
          unsigned long long hp[4];
          #pragma unroll
          for (int rg = 0; rg < 4; ++rg) {
            float iv = accB[0][nt][rg] + bbv[rg];
            float gv = accB[1][nt][rg] + bbv[4+rg];
            float ov = accB[2][nt][rg] + bbv[8+rg];
            float c  = sigf(iv) * tanh_fast(gv);
            float h  = sigf(ov) * tanh_fast(c);
            hp[rg] = (unsigned long long)f2bf(h);
          }
          unsigned long long v = hp[0] | (hp[1] << 16) | (hp[2] << 32) | (hp[3] << 48);
          size_t off = ((size_t)(w >> 1)*128 + bcol)*32 + (w & 1)*16 + lg*4;
          *(unsigned long long*)(xA_wr + off) = v;   // local
          pv[nt] = v; poff[nt] = off;
        }
      }
      lbar_arrive(lfl, w, 2u*t + 2);         // local h1 visible; release stage A(t+1)
      // lazy MALL push for y (drained by next step's stage-A vmcnt(0))
      st_mall_u64(xAm_wr + poff[0], pv[0]);
      st_mall_u64(xAm_wr + poff[1], pv[1]);
      if (t + 1 < T_) featPart(4, 8, t + 1);
    }
    // epilogue: publish final MALL flag (covers h1(T-1) pushes)
    asm volatile("s_waitcnt vmcnt(0)" ::: "memory");
    __syncthreads();
    if (tid == 0)
      (void)__hip_atomic_exchange(mfl + (size_t)w*16, (unsigned)T_, __ATOMIC_RELAXED, __HIP_MEMORY_SCOPE_AGENT);
  } else {
    // ==================== y WGs: y(t-1) = h1(t-1) @ lin_W.T + lin_b ====================
    for (int t = 1; t <= T_; ++t) {
      ybar_wait(mfl, (unsigned)t);           // h1(t-1) at MALL
      const unsigned short* xAm_rd = xAmr + ((size_t)((t-1) & (RROTM-1))*2 + branch)*B_*H_;
      uint4 bs[2][16];
      #pragma unroll
      for (int nt = 0; nt < 2; ++nt) {
        const int n = (wv*2 + nt)*16 + ln;
        const unsigned short* base = xAm_rd + (size_t)n*32 + lg*8;
        #pragma unroll
        for (int kt = 0; kt < 16; ++kt)
          bs[nt][kt] = *(const uint4*)(base + (size_t)kt*4096);
      }
      f32x4 acc[2][2];
      acc[0][0]=zv; acc[0][1]=zv; acc[1][0]=zv; acc[1][1]=zv;
      #pragma unroll
      for (int kt = 0; kt < 16; ++kt) {
        #pragma unroll
        for (int mt = 0; mt < 2; ++mt) {
          short8 afr = *(const short8*)(lds + ((mt*16 + kt)*64 + l)*16);
          #pragma unroll
          for (int nt = 0; nt < 2; ++nt)
            acc[mt][nt] = __builtin_amdgcn_mfma_f32_16x16x32_bf16(
                __builtin_bit_cast(bf16x8, afr),
                __builtin_bit_cast(bf16x8, __builtin_bit_cast(u32x4, bs[nt][kt])),
                acc[mt][nt], 0, 0, 0);
        }
      }
      #pragma unroll
      for (int mt = 0; mt < 2; ++mt)
        #pragma unroll
        for (int nt = 0; nt < 2; ++nt) {
          const int bcol = (wv*2 + nt)*16 + ln;
          float4 o;
          o.x = acc[mt][nt][0] + by[mt*4+0];
          o.y = acc[mt][nt][1] + by[mt*4+1];
          o.z = acc[mt][nt][2] + by[mt*4+2];
          o.w = acc[mt][nt][3] + by[mt*4+3];
          *(float4*)(out + (size_t)branch*TBE_ + ((size_t)(t-1)*B_ + bcol)*E_ + 32*w + mt*16 + 4*lg) = o;
        }
    }
  }
}

// ======================= launch =======================

extern "C" void kernel_launch(void* const* d_in, const int* in_sizes, int n_in,
                              void* d_out, int out_size, void* d_ws, size_t ws_size,
                              hipStream_t stream) {
  (void)in_sizes; (void)n_in; (void)out_size; (void)ws_size;
  const float* upF  = (const float*)d_in[0];
  const float* loF  = (const float*)d_in[1];
  const float* uW0  = (const float*)d_in[2];
  const float* ubi0 = (const float*)d_in[3];
  const float* ubh0 = (const float*)d_in[4];
  const float* uW1  = (const float*)d_in[5];
  const float* ubi1 = (const float*)d_in[6];
  const float* ubh1 = (const float*)d_in[7];
  const float* lW0  = (const float*)d_in[8];
  const float* lbi0 = (const float*)d_in[9];
  const float* lbh0 = (const float*)d_in[10];
  const float* lW1  = (const float*)d_in[11];
  const float* lbi1 = (const float*)d_in[12];
  const float* lbh1 = (const float*)d_in[13];
  const float* linW = (const float*)d_in[14];
  const float* linb = (const float*)d_in[15];
  float* out = (float*)d_out;
  unsigned char* ws = (unsigned char*)d_ws;

  unsigned short* WAf = (unsigned short*)(ws + OFF_WA);
  unsigned short* WYf = (unsigned short*)(ws + OFF_WY);
  unsigned short* WBf = (unsigned short*)(ws + OFF_WB);
  float* bA0 = (float*)(ws + OFF_BA0);
  float* bA1 = (float*)(ws + OFF_BA1);
  float* bBv = (float*)(ws + OFF_BBv);

  hipMemsetAsync(d_ws, 0, 12288, stream);   // zero local flags + MALL flags + tickets

  k_pack_wc<<<dim3(2*1536), dim3(256), 0, stream>>>(uW0, lW0, linW, WAf);
  k_pack_rest<<<dim3(2*1536), dim3(256), 0, stream>>>(uW0, ubi0, ubh0, uW1, ubi1, ubh1,
                                                      lW0, lbi0, lbh0, lW1, lbi1, lbh1,
                                                      linb, WAf, WBf, bA0, bA1, bBv);
  k_pack_wy<<<dim3(256), dim3(256), 0, stream>>>(linW, WYf);

  hipFuncSetAttribute((const void*)k_rnn, hipFuncAttributeMaxDynamicSharedMemorySize, LDS_BYTES);
  k_rnn<<<dim3(256), dim3(256), LDS_BYTES, stream>>>(upF, loF, linb, out, ws);
}

// Round 11
// 19744.246 us; speedup vs baseline: 1.0118x; 1.0118x over previous
//
#include <hip/hip_runtime.h>
#include <hip/hip_bf16.h>

// Problem constants
#define E_   256
#define H_   512
#define T_   512
#define B_   128
#define TBE_ (T_*B_*E_)

#define GW 32               // gate WGs per branch (one full XCD)
#define YW 8                // y WGs per branch (anywhere else)
#define RROT 4              // local state rotation
#define RROTM 8             // MALL h1 copy rotation (y lag cushion)
#define LDS_BYTES 122880    // 73728 (stage-A frags) + 49152 (stage-B frags)

typedef __attribute__((ext_vector_type(4))) float  f32x4;
typedef __attribute__((ext_vector_type(8))) __bf16 bf16x8;
typedef __attribute__((ext_vector_type(8))) short  short8;
typedef __attribute__((ext_vector_type(4))) unsigned int u32x4;

// ---- workspace layout (bytes) ----
#define OFF_LF0  0          // branch0 local flags: 32 x 64B
#define OFF_LF1  2048       // branch1 local flags
#define OFF_MF0  4096       // branch0 MALL flags: 32 x 64B
#define OFF_MF1  6144       // branch1 MALL flags
#define OFF_TICK 8192       // 4 ticket counters (16B)
#define OFF_WA   12288                         // stage-A frag weights [2][32][3][24][64][8] bf16
#define SZ_WA    (2*GW*3*24*64*8*2)            // 4,718,592
#define OFF_WY   (OFF_WA + SZ_WA)              // y frag weights
#define SZ_WY    (YW*2*16*64*8*2)              // 262,144
#define OFF_WB   (OFF_WY + SZ_WY)              // stage-B frag weights
#define SZ_WB    (2*GW*3*16*64*8*2)            // 3,145,728
#define OFF_BA0  (OFF_WB + SZ_WB)
#define OFF_BA1  (OFF_BA0 + 2*1536*4)
#define OFF_BBv  (OFF_BA1 + 2*1536*4)
#define OFF_XA   (OFF_BBv + 2*1536*4)          // local h1 [RROT][2][16][128][32] bf16
#define SZ_XL    (RROT*2*B_*H_*2)              // 1,048,576
#define OFF_XB   (OFF_XA + SZ_XL)              // local h0, same layout
#define OFF_XAM  (OFF_XB + SZ_XL)              // MALL h1 copy [RROTM][2][...]
#define SZ_XAM   (RROTM*2*B_*H_*2)             // 2,097,152
#define WS_NEED  (OFF_XAM + SZ_XAM)            // ~12.4 MB

__device__ __host__ inline int gate_src_row(int p) {
  // packed row p in [0,1536): w=p/48 slice, r=p%48: [0,16)=i, [16,32)=g, [32,48)=o
  int w = p / 48, r = p % 48;
  int grp = r >> 4;
  int idx = r & 15;
  int base = (grp == 0) ? 0 : (grp == 1 ? 1024 : 1536);
  return base + 16*w + idx;
}

__device__ inline unsigned short f2bf(float f) {   // RNE f32->bf16
  unsigned u = __float_as_uint(f);
  u += 0x7fffu + ((u >> 16) & 1u);
  return (unsigned short)(u >> 16);
}
__device__ inline float sigf(float x)      { return __builtin_amdgcn_rcpf(1.f + __expf(-x)); }
__device__ inline float tanh_fast(float x) { return 1.f - 2.f*__builtin_amdgcn_rcpf(1.f + __expf(2.f*x)); }

__device__ inline unsigned pk2(float a, float b) {   // v_cvt_pk_bf16_f32 (RNE)
  unsigned r;
  asm("v_cvt_pk_bf16_f32 %0, %1, %2" : "=v"(r) : "v"(a), "v"(b));
  return r;
}

// MALL push (y-path only): r3/r5/r8-proven compiler atomic exchange.
__device__ inline void st_mall_u64(unsigned short* p, unsigned long long v) {
  (void)__hip_atomic_exchange((unsigned long long*)p, v, __ATOMIC_RELAXED, __HIP_MEMORY_SCOPE_AGENT);
}

// ---- XCD-local ops ----
// Same-XCD CUs share one L2. Producer plain stores land in that L2 (L1 is
// write-through); vmcnt(0) before the flag orders them. Consumer loads with
// sc0 (SE scope) bypass the per-CU L1 and are served by the shared L2 -> no
// fences needed on the poll path (r10's per-spin-iteration buffer_inv storm
// was the 2.4x regression). A once-per-phase fence remains as the belt.
__device__ inline unsigned get_xcc() {
  unsigned x;
  asm volatile("s_getreg_b32 %0, hwreg(HW_REG_XCC_ID)" : "=s"(x));
  return x;
}
__device__ inline u32x4 ld_l2_b128(const unsigned short* p) {   // not vmcnt-tracked by compiler
  u32x4 r;
  asm volatile("global_load_dwordx4 %0, %1, off sc0" : "=&v"(r) : "v"(p) : "memory");
  return r;
}
__device__ inline unsigned ld_l2_u32(const unsigned* p) {
  unsigned v;
  asm volatile("global_load_dword %0, %1, off sc0\n\ts_waitcnt vmcnt(0)"
               : "=&v"(v) : "v"(p) : "memory");
  return v;
}
__device__ inline void wait_vm0() {
  asm volatile("s_waitcnt vmcnt(0)" ::: "memory");
  __builtin_amdgcn_sched_barrier(0);   // rule #18: MFMAs must not hoist above
}

__device__ inline void lbar_arrive(unsigned* lfl, int w, unsigned phase) {
  asm volatile("s_waitcnt vmcnt(0)" ::: "memory");   // data stores in shared L2 first
  __syncthreads();
  if (threadIdx.x == 0) {
    __builtin_amdgcn_sched_barrier(0);
    *(volatile unsigned*)(lfl + (size_t)w*16) = phase;
  }
}
__device__ inline void lbar_arrive_m(unsigned* lfl, unsigned* mfl, int w, unsigned phase, unsigned mval) {
  asm volatile("s_waitcnt vmcnt(0)" ::: "memory");   // also drains prior MALL pushes
  __syncthreads();
  if (threadIdx.x == 0) {
    __builtin_amdgcn_sched_barrier(0);
    *(volatile unsigned*)(lfl + (size_t)w*16) = phase;
    (void)__hip_atomic_exchange(mfl + (size_t)w*16, mval, __ATOMIC_RELAXED, __HIP_MEMORY_SCOPE_AGENT);
  }
}
__device__ inline void lbar_wait(unsigned* lfl, unsigned phase) {
  if (threadIdx.x < 64) {
    const unsigned* p = lfl + (size_t)(threadIdx.x & 31)*16;
    int spins = 0;
    for (;;) {
      unsigned v = ld_l2_u32(p);               // L1-bypass poll, zero invalidates
      if (__all(v >= phase)) break;
      if (((++spins) & 1023) == 1023)
        __builtin_amdgcn_fence(__ATOMIC_ACQUIRE, "agent");   // hedge: cannot hang
    }
  }
  __syncthreads();
  __builtin_amdgcn_fence(__ATOMIC_ACQUIRE, "agent");   // once/phase: L1 inv belt
  __builtin_amdgcn_sched_barrier(0);
}

// y-side MALL flag poll (r5-proven sc0sc1 pattern; monotonic -> stale just spins)
__device__ inline unsigned mall_poll(const unsigned* p) {
  unsigned v;
  asm volatile("global_load_dword %0, %1, off sc0 sc1\n\ts_waitcnt vmcnt(0)"
               : "=&v"(v) : "v"(p) : "memory");
  return v;
}
__device__ inline void ybar_wait(unsigned* mfl, unsigned need) {
  if (threadIdx.x < 64) {
    unsigned* p = mfl + (size_t)(threadIdx.x & 31)*16;
    int spins = 0;
    for (;;) {
      unsigned v = mall_poll(p);
      if (__all(v >= need)) break;
      if (((++spins) & 255) == 255) {
        unsigned a = __hip_atomic_fetch_add(p, 0u, __ATOMIC_RELAXED, __HIP_MEMORY_SCOPE_AGENT);
        if (__all(a >= need)) break;
      }
    }
  }
  __syncthreads();
  __builtin_amdgcn_fence(__ATOMIC_ACQUIRE, "agent");   // drop clean xAm lines
  __builtin_amdgcn_sched_barrier(0);
}

// ======================= weight packing (fragment order) =======================
// frag elem index within a WG slice: ((mt*KT + kt)*64 + lane)*8 + e
// lane = lg*16 + ln holds row (mt*16+ln), k = kt*32 + lg*8 + e

__global__ __launch_bounds__(256) void k_pack_wc(const float* __restrict__ uW0, const float* __restrict__ lW0,
                                                 const float* __restrict__ linW, unsigned short* __restrict__ WAf) {
  int blk = blockIdx.x;                 // 2*1536 blocks
  int branch = blk / 1536, p = blk % 1536;
  const float* W0 = branch ? lW0 : uW0;
  int s = gate_src_row(p);
  int w = p / 48, rr = p % 48, mt = rr >> 4, ln = rr & 15;
  __shared__ float a[256];
  int tid = threadIdx.x;
  a[tid] = W0[(size_t)s*512 + tid];     // W0p row (cols 0:256 = prev-embed part)
  __syncthreads();
  size_t baseA = (((size_t)(branch*GW + w)*3 + mt)*24) * 64 * 8;
  for (int kk = 0; kk < 2; ++kk) {
    int k = kk*256 + tid;
    float acc = 0.f;
    #pragma unroll 8
    for (int e = 0; e < 256; ++e) acc = fmaf(a[e], linW[(size_t)e*512 + k], acc);
    int kt = k >> 5, lg = (k >> 3) & 3, e = k & 7;
    WAf[baseA + ((size_t)kt*64 + lg*16 + ln)*8 + e] = f2bf(acc);
  }
}

__global__ __launch_bounds__(256) void k_pack_rest(
    const float* __restrict__ uW0, const float* __restrict__ ubi0, const float* __restrict__ ubh0,
    const float* __restrict__ uW1, const float* __restrict__ ubi1, const float* __restrict__ ubh1,
    const float* __restrict__ lW0, const float* __restrict__ lbi0, const float* __restrict__ lbh0,
    const float* __restrict__ lW1, const float* __restrict__ lbi1, const float* __restrict__ lbh1,
    const float* __restrict__ linb,
    unsigned short* __restrict__ WAf, unsigned short* __restrict__ WBf,
    float* __restrict__ bA0, float* __restrict__ bA1, float* __restrict__ bBv) {
  int blk = blockIdx.x;
  int branch = blk / 1536, p = blk % 1536;
  const float* W0  = branch ? lW0  : uW0;
  const float* bi0 = branch ? lbi0 : ubi0;
  const float* bh0 = branch ? lbh0 : ubh0;
  const float* W1  = branch ? lW1  : uW1;
  const float* bi1 = branch ? lbi1 : ubi1;
  const float* bh1 = branch ? lbh1 : ubh1;
  int s = gate_src_row(p);
  int w = p / 48, rr = p % 48, mt = rr >> 4, ln = rr & 15;
  int tid = threadIdx.x;
  size_t baseA = (((size_t)(branch*GW + w)*3 + mt)*24) * 64 * 8;
  size_t baseB = (((size_t)(branch*GW + w)*3 + mt)*16) * 64 * 8;
  {  // W0f (feat part) -> kt 16..23
    int c = tid;
    int kt = 16 + (c >> 5), lg = (c >> 3) & 3, e = c & 7;
    WAf[baseA + ((size_t)kt*64 + lg*16 + ln)*8 + e] = f2bf(W0[(size_t)s*512 + 256 + c]);
  }
  for (int half = 0; half < 2; ++half) {
    int k = half*256 + tid;
    int kt = k >> 5, lg = (k >> 3) & 3, e = k & 7;
    WBf[baseB + ((size_t)kt*64 + lg*16 + ln)*8 + e] = f2bf(W1[(size_t)s*512 + k]);
  }
  __shared__ float red[256];
  red[tid] = W0[(size_t)s*512 + tid] * linb[tid];   // c0 = W0p @ lin_b
  __syncthreads();
  for (int st = 128; st > 0; st >>= 1) { if (tid < st) red[tid] += red[tid + st]; __syncthreads(); }
  if (tid == 0) {
    size_t rowA = (size_t)branch*1536 + p;
    float b0 = bi0[s] + bh0[s];
    bA0[rowA] = b0;
    bA1[rowA] = b0 + red[0];
    bBv[rowA] = bi1[s] + bh1[s];
  }
}

__global__ __launch_bounds__(256) void k_pack_wy(const float* __restrict__ linW, unsigned short* __restrict__ WYf) {
  int row = blockIdx.x;                 // 256 blocks
  int w2 = row >> 5, rr = row & 31, mt = rr >> 4, ln = rr & 15;
  int tid = threadIdx.x;
  size_t base = ((size_t)(w2*2 + mt)*16) * 64 * 8;
  for (int half = 0; half < 2; ++half) {
    int k = half*256 + tid;
    int kt = k >> 5, lg = (k >> 3) & 3, e = k & 7;
    WYf[base + ((size_t)kt*64 + lg*16 + ln)*8 + e] = f2bf(linW[(size_t)row*512 + k]);
  }
}

// ======================= persistent recurrent kernel =======================

__global__ __launch_bounds__(256, 1) void k_rnn(
    const float* __restrict__ featU, const float* __restrict__ featL,
    const float* __restrict__ linb,
    float* __restrict__ out, unsigned char* __restrict__ ws) {

  extern __shared__ unsigned char lds[];
  __shared__ int sRole;

  const int tid = threadIdx.x;
  // ---- mapping-independent role assignment: ticket per ACTUAL XCD ----
  if (tid == 0) {
    unsigned xcc = get_xcc();
    int enc = -1;
    unsigned* tick = (unsigned*)(ws + OFF_TICK);
    if (xcc < 2) {      // gate XCDs: branch = xcc
      unsigned r = __hip_atomic_fetch_add(&tick[xcc], 1u, __ATOMIC_RELAXED, __HIP_MEMORY_SCOPE_AGENT);
      if (r < GW) enc = (int)(xcc*64 + r);
    } else {            // y pool: first 16 tickets -> 8 per branch
      unsigned r = __hip_atomic_fetch_add(&tick[2], 1u, __ATOMIC_RELAXED, __HIP_MEMORY_SCOPE_AGENT);
      if (r < 2*YW) enc = (int)((r >> 3)*64 + 32 + (r & 7));
    }
    sRole = enc;
  }
  __syncthreads();
  const int enc = sRole;
  if (enc < 0) return;
  const int branch = enc >> 6;
  const int role   = enc & 63;
  const bool isGate = role < 32;
  const int w = isGate ? role : (role - 32);
  const float* feat = branch ? featL : featU;

  const unsigned short* WAf = (const unsigned short*)(ws + OFF_WA);
  const unsigned short* WYf = (const unsigned short*)(ws + OFF_WY);
  const unsigned short* WBf = (const unsigned short*)(ws + OFF_WB);
  const float* bA0 = (const float*)(ws + OFF_BA0) + branch*1536;
  const float* bA1 = (const float*)(ws + OFF_BA1) + branch*1536;
  const float* bBv = (const float*)(ws + OFF_BBv) + branch*1536;
  unsigned short* xAr  = (unsigned short*)(ws + OFF_XA);    // local h1 slots
  unsigned short* xBr  = (unsigned short*)(ws + OFF_XB);    // local h0 slots
  unsigned short* xAmr = (unsigned short*)(ws + OFF_XAM);   // MALL h1 slots
  unsigned* lfl = (unsigned*)(ws + (branch ? OFF_LF1 : OFF_LF0));
  unsigned* mfl = (unsigned*)(ws + (branch ? OFF_MF1 : OFF_MF0));

  const int l   = tid & 63;
  const int wv  = tid >> 6;   // wave 0..3
  const int lg  = l >> 4;     // k-subgroup 0..3
  const int ln  = l & 15;     // row/col in tile

  // ---- stage weights into LDS ----
  if (isGate) {
    const uint4* srcA = (const uint4*)(WAf + (size_t)(branch*GW + w)*36864);
    uint4* dA = (uint4*)lds;
    for (int i = tid; i < 4608; i += 256) dA[i] = srcA[i];
    const uint4* srcB = (const uint4*)(WBf + (size_t)(branch*GW + w)*24576);
    uint4* dB = (uint4*)(lds + 73728);
    for (int i = tid; i < 3072; i += 256) dB[i] = srcB[i];
  } else {
    const uint4* srcY = (const uint4*)(WYf + (size_t)w*16384);
    uint4* dY = (uint4*)lds;
    for (int i = tid; i < 2048; i += 256) dY[i] = srcY[i];
  }

  // ---- per-lane bias preload ----
  float ba0[12], ba1[12], bbv[12], by[8];
  if (isGate) {
    #pragma unroll
    for (int mt = 0; mt < 3; ++mt)
      #pragma unroll
      for (int rg = 0; rg < 4; ++rg) {
        int p = 48*w + mt*16 + 4*lg + rg;
        ba0[mt*4+rg] = bA0[p];
        ba1[mt*4+rg] = bA1[p];
        bbv[mt*4+rg] = bBv[p];
      }
  } else {
    #pragma unroll
    for (int mt = 0; mt < 2; ++mt)
      #pragma unroll
      for (int rg = 0; rg < 4; ++rg)
        by[mt*4+rg] = linb[32*w + mt*16 + 4*lg + rg];
  }
  __syncthreads();

  const f32x4 zv = {0.f, 0.f, 0.f, 0.f};

  if (isGate) {
    // featN: pre-accumulated feat-part of stage A for the NEXT timestep
    f32x4 featN[3][2];
    #pragma unroll
    for (int mt = 0; mt < 3; ++mt) { featN[mt][0] = zv; featN[mt][1] = zv; }

    auto featPart = [&](int lo, int hi, int tt) {
      for (int kt2 = lo; kt2 < hi; ++kt2) {
        short8 bfr[2];
        #pragma unroll
        for (int nt = 0; nt < 2; ++nt) {
          const int n = (wv*2 + nt)*16 + ln;
          const float* pf = feat + ((size_t)n*T_ + tt)*E_ + kt2*32 + 8*lg;
          float4 f0 = *(const float4*)pf;
          float4 f1 = *(const float4*)(pf + 4);
          u32x4 pk;
          pk.x = pk2(f0.x, f0.y); pk.y = pk2(f0.z, f0.w);
          pk.z = pk2(f1.x, f1.y); pk.w = pk2(f1.z, f1.w);
          bfr[nt] = __builtin_bit_cast(short8, pk);
        }
        #pragma unroll
        for (int mt = 0; mt < 3; ++mt) {
          short8 afr = *(const short8*)(lds + ((mt*24 + 16 + kt2)*64 + l)*16);
          #pragma unroll
          for (int nt = 0; nt < 2; ++nt)
            featN[mt][nt] = __builtin_amdgcn_mfma_f32_16x16x32_bf16(
                __builtin_bit_cast(bf16x8, afr), __builtin_bit_cast(bf16x8, bfr[nt]),
                featN[mt][nt], 0, 0, 0);
        }
      }
    };

    featPart(0, 8, 0);

    for (int t = 0; t < T_; ++t) {
      const unsigned short* xA_rd = xAr + ((size_t)((t-1) & (RROT-1))*2 + branch)*B_*H_;
      unsigned short*       xB_wr = xBr + ((size_t)(t & (RROT-1))*2 + branch)*B_*H_;
      const unsigned short* xB_rd = xB_wr;
      unsigned short*       xA_wr = xAr + ((size_t)(t & (RROT-1))*2 + branch)*B_*H_;
      unsigned short*       xAm_wr = xAmr + ((size_t)(t & (RROTM-1))*2 + branch)*B_*H_;

      // ---------------- stage A: h0(t) = act(Wc@h1(t-1) + featN + bias) ----------------
      f32x4 acc[3][2];
      #pragma unroll
      for (int mt = 0; mt < 3; ++mt)
        #pragma unroll
        for (int nt = 0; nt < 2; ++nt) { acc[mt][nt] = featN[mt][nt]; featN[mt][nt] = zv; }

      if (t > 0) {
        lbar_wait(lfl, 2u*t);                // h1(t-1) in shared local L2
        u32x4 bs[2][16];                     // asm sc0 loads: ALL 32 in flight
        #pragma unroll
        for (int nt = 0; nt < 2; ++nt) {
          const int n = (wv*2 + nt)*16 + ln;
          const unsigned short* base = xA_rd + (size_t)n*32 + lg*8;
          #pragma unroll
          for (int kt = 0; kt < 16; ++kt)
            bs[nt][kt] = ld_l2_b128(base + (size_t)kt*4096);
        }
        wait_vm0();
        #pragma unroll
        for (int kt = 0; kt < 16; ++kt) {
          #pragma unroll
          for (int mt = 0; mt < 3; ++mt) {
            short8 afr = *(const short8*)(lds + ((mt*24 + kt)*64 + l)*16);
            #pragma unroll
            for (int nt = 0; nt < 2; ++nt)
              acc[mt][nt] = __builtin_amdgcn_mfma_f32_16x16x32_bf16(
                  __builtin_bit_cast(bf16x8, afr),
                  __builtin_bit_cast(bf16x8, bs[nt][kt]),
                  acc[mt][nt], 0, 0, 0);
          }
        }
      }
      {
        float bcur[12];
        #pragma unroll
        for (int q = 0; q < 12; ++q) bcur[q] = (t == 0) ? ba0[q] : ba1[q];
        #pragma unroll
        for (int nt = 0; nt < 2; ++nt) {
          const int bcol = (wv*2 + nt)*16 + ln;
          unsigned long long hp[4];
          #pragma unroll
          for (int rg = 0; rg < 4; ++rg) {
            float iv = acc[0][nt][rg] + bcur[rg];
            float gv = acc[1][nt][rg] + bcur[4+rg];
            float ov = acc[2][nt][rg] + bcur[8+rg];
            float c  = sigf(iv) * tanh_fast(gv);
            float h  = sigf(ov) * tanh_fast(c);
            hp[rg] = (unsigned long long)f2bf(h);
          }
          unsigned long long v = hp[0] | (hp[1] << 16) | (hp[2] << 32) | (hp[3] << 48);
          *(unsigned long long*)(xB_wr + ((size_t)(w >> 1)*128 + bcol)*32 + (w & 1)*16 + lg*4) = v;
        }
      }
      // vmcnt(0) drains h0 stores AND step-(t-1) MALL pushes -> mflag=t is safe
      lbar_arrive_m(lfl, mfl, w, 2u*t + 1, (unsigned)t);
      if (t + 1 < T_) featPart(0, 4, t + 1);
      lbar_wait(lfl, 2u*t + 1);              // h0(t) in shared local L2

      // ---------------- stage B: h1(t) = act(W1@h0(t) + bias) ----------------
      unsigned long long pv[2]; size_t poff[2];
      {
        u32x4 cs[2][16];
        #pragma unroll
        for (int nt = 0; nt < 2; ++nt) {
          const int n = (wv*2 + nt)*16 + ln;
          const unsigned short* base = xB_rd + (size_t)n*32 + lg*8;
          #pragma unroll
          for (int kt = 0; kt < 16; ++kt)
            cs[nt][kt] = ld_l2_b128(base + (size_t)kt*4096);
        }
        f32x4 accB[3][2];
        #pragma unroll
        for (int mt = 0; mt < 3; ++mt) { accB[mt][0] = zv; accB[mt][1] = zv; }
        wait_vm0();
        #pragma unroll
        for (int kt = 0; kt < 16; ++kt) {
          #pragma unroll
          for (int mt = 0; mt < 3; ++mt) {
            short8 afr = *(const short8*)(lds + 73728 + ((mt*16 + kt)*64 + l)*16);
            #pragma unroll
            for (int nt = 0; nt < 2; ++nt)
              accB[mt][nt] = __builtin_amdgcn_mfma_f32_16x16x32_bf16(
                  __builtin_bit_cast(bf16x8, afr),
                  __builtin_bit_cast(bf16x8, cs[nt][kt]),
                  accB[mt][nt], 0, 0, 0);
          }
        }
        #pragma unroll
        for (int nt = 0; nt < 2; ++nt) {
          const int bcol = (wv*2 + nt)*16 + ln;
          unsigned long long hp[4];
          #pragma unroll
          for (int rg = 0; rg < 4; ++rg) {
            float iv = accB[0][nt][rg] + bbv[rg];
            float gv = accB[1][nt][rg] + bbv[4+rg];
            float ov = accB[2][nt][rg] + bbv[8+rg];
            float c  = sigf(iv) * tanh_fast(gv);
            float h  = sigf(ov) * tanh_fast(c);
            hp[rg] = (unsigned long long)f2bf(h);
          }
          unsigned long long v = hp[0] | (hp[1] << 16) | (hp[2] << 32) | (hp[3] << 48);
          size_t off = ((size_t)(w >> 1)*128 + bcol)*32 + (w & 1)*16 + lg*4;
          *(unsigned long long*)(xA_wr + off) = v;   // local
          pv[nt] = v; poff[nt] = off;
        }
      }
      lbar_arrive(lfl, w, 2u*t + 2);         // local h1 visible; release stage A(t+1)
      // lazy MALL push for y (drained by next step's lbar_arrive_m vmcnt(0))
      st_mall_u64(xAm_wr + poff[0], pv[0]);
      st_mall_u64(xAm_wr + poff[1], pv[1]);
      if (t + 1 < T_) featPart(4, 8, t + 1);
    }
    // epilogue: publish final MALL flag (covers h1(T-1) pushes)
    asm volatile("s_waitcnt vmcnt(0)" ::: "memory");
    __syncthreads();
    if (tid == 0)
      (void)__hip_atomic_exchange(mfl + (size_t)w*16, (unsigned)T_, __ATOMIC_RELAXED, __HIP_MEMORY_SCOPE_AGENT);
  } else {
    // ==================== y WGs: y(t-1) = h1(t-1) @ lin_W.T + lin_b ====================
    for (int t = 1; t <= T_; ++t) {
      ybar_wait(mfl, (unsigned)t);           // h1(t-1) at MALL
      const unsigned short* xAm_rd = xAmr + ((size_t)((t-1) & (RROTM-1))*2 + branch)*B_*H_;
      uint4 bs[2][16];
      #pragma unroll
      for (int nt = 0; nt < 2; ++nt) {
        const int n = (wv*2 + nt)*16 + ln;
        const unsigned short* base = xAm_rd + (size_t)n*32 + lg*8;
        #pragma unroll
        for (int kt = 0; kt < 16; ++kt)
          bs[nt][kt] = *(const uint4*)(base + (size_t)kt*4096);
      }
      f32x4 acc[2][2];
      acc[0][0]=zv; acc[0][1]=zv; acc[1][0]=zv; acc[1][1]=zv;
      #pragma unroll
      for (int kt = 0; kt < 16; ++kt) {
        #pragma unroll
        for (int mt = 0; mt < 2; ++mt) {
          short8 afr = *(const short8*)(lds + ((mt*16 + kt)*64 + l)*16);
          #pragma unroll
          for (int nt = 0; nt < 2; ++nt)
            acc[mt][nt] = __builtin_amdgcn_mfma_f32_16x16x32_bf16(
                __builtin_bit_cast(bf16x8, afr),
                __builtin_bit_cast(bf16x8, __builtin_bit_cast(u32x4, bs[nt][kt])),
                acc[mt][nt], 0, 0, 0);
        }
      }
      #pragma unroll
      for (int mt = 0; mt < 2; ++mt)
        #pragma unroll
        for (int nt = 0; nt < 2; ++nt) {
          const int bcol = (wv*2 + nt)*16 + ln;
          float4 o;
          o.x = acc[mt][nt][0] + by[mt*4+0];
          o.y = acc[mt][nt][1] + by[mt*4+1];
          o.z = acc[mt][nt][2] + by[mt*4+2];
          o.w = acc[mt][nt][3] + by[mt*4+3];
          *(float4*)(out + (size_t)branch*TBE_ + ((size_t)(t-1)*B_ + bcol)*E_ + 32*w + mt*16 + 4*lg) = o;
        }
    }
  }
}

// ======================= launch =======================

extern "C" void kernel_launch(void* const* d_in, const int* in_sizes, int n_in,
                              void* d_out, int out_size, void* d_ws, size_t ws_size,
                              hipStream_t stream) {
  (void)in_sizes; (void)n_in; (void)out_size; (void)ws_size;
  const float* upF  = (const float*)d_in[0];
  const float* loF  = (const float*)d_in[1];
  const float* uW0  = (const float*)d_in[2];
  const float* ubi0 = (const float*)d_in[3];
  const float* ubh0 = (const float*)d_in[4];
  const float* uW1  = (const float*)d_in[5];
  const float* ubi1 = (const float*)d_in[6];
  const float* ubh1 = (const float*)d_in[7];
  const float* lW0  = (const float*)d_in[8];
  const float* lbi0 = (const float*)d_in[9];
  const float* lbh0 = (const float*)d_in[10];
  const float* lW1  = (const float*)d_in[11];
  const float* lbi1 = (const float*)d_in[12];
  const float* lbh1 = (const float*)d_in[13];
  const float* linW = (const float*)d_in[14];
  const float* linb = (const float*)d_in[15];
  float* out = (float*)d_out;
  unsigned char* ws = (unsigned char*)d_ws;

  unsigned short* WAf = (unsigned short*)(ws + OFF_WA);
  unsigned short* WYf = (unsigned short*)(ws + OFF_WY);
  unsigned short* WBf = (unsigned short*)(ws + OFF_WB);
  float* bA0 = (float*)(ws + OFF_BA0);
  float* bA1 = (float*)(ws + OFF_BA1);
  float* bBv = (float*)(ws + OFF_BBv);

  hipMemsetAsync(d_ws, 0, 12288, stream);   // zero local flags + MALL flags + tickets

  k_pack_wc<<<dim3(2*1536), dim3(256), 0, stream>>>(uW0, lW0, linW, WAf);
  k_pack_rest<<<dim3(2*1536), dim3(256), 0, stream>>>(uW0, ubi0, ubh0, uW1, ubi1, ubh1,
                                                      lW0, lbi0, lbh0, lW1, lbi1, lbh1,
                                                      linb, WAf, WBf, bA0, bA1, bBv);
  k_pack_wy<<<dim3(256), dim3(256), 0, stream>>>(linW, WYf);

  hipFuncSetAttribute((const void*)k_rnn, hipFuncAttributeMaxDynamicSharedMemorySize, LDS_BYTES);
  k_rnn<<<dim3(256), dim3(256), LDS_BYTES, stream>>>(upF, loF, linb, out, ws);
}

// Round 12
// 8383.755 us; speedup vs baseline: 2.3828x; 2.3551x over previous
//
#include <hip/hip_runtime.h>
#include <hip/hip_bf16.h>

// Problem constants
#define E_   256
#define H_   512
#define T_   512
#define B_   128
#define TBE_ (T_*B_*E_)

#define GW 32               // gate WGs per branch
#define YW 8                // y WGs per branch
#define NWG 80              // 2 * (GW + YW)
#define RROTA 8             // h1 rotation (y reads with lag cushion)
#define RROTB 4             // h0 rotation (gate-internal)
#define LDS_BYTES 122880    // 73728 (stage-A frags) + 49152 (stage-B frags)

typedef __attribute__((ext_vector_type(4))) float  f32x4;
typedef __attribute__((ext_vector_type(8))) __bf16 bf16x8;
typedef __attribute__((ext_vector_type(8))) short  short8;
typedef __attribute__((ext_vector_type(4))) unsigned int u32x4;

// ---- workspace layout (bytes) ----
// per-branch gate flags: 32 x 64B at ws+0 / ws+2048 (memset 8192 covers)
#define OFF_FL0  0
#define OFF_FL1  2048
#define OFF_WA   8192                          // stage-A frag weights [2][32][3][24][64][8] bf16
#define SZ_WA    (2*GW*3*24*64*8*2)            // 4,718,592
#define OFF_WY   (OFF_WA + SZ_WA)              // y frag weights
#define SZ_WY    (YW*2*16*64*8*2)              // 262,144
#define OFF_WB   (OFF_WY + SZ_WY)              // stage-B frag weights
#define SZ_WB    (2*GW*3*16*64*8*2)            // 3,145,728
#define OFF_BA0  (OFF_WB + SZ_WB)
#define OFF_BA1  (OFF_BA0 + 2*1536*4)
#define OFF_BBv  (OFF_BA1 + 2*1536*4)
#define OFF_XA   (OFF_BBv + 2*1536*4)          // h1 state [RROTA][2][16][128][32] bf16
#define SZ_XA    (RROTA*2*B_*H_*2)             // 2,097,152
#define OFF_XB   (OFF_XA + SZ_XA)              // h0 state [RROTB][2][...]
#define SZ_XB    (RROTB*2*B_*H_*2)             // 1,048,576
#define WS_NEED  (OFF_XB + SZ_XB)              // ~11.4 MB

__device__ __host__ inline int gate_src_row(int p) {
  // packed row p in [0,1536): w=p/48 slice, r=p%48: [0,16)=i, [16,32)=g, [32,48)=o
  int w = p / 48, r = p % 48;
  int grp = r >> 4;
  int idx = r & 15;
  int base = (grp == 0) ? 0 : (grp == 1 ? 1024 : 1536);
  return base + 16*w + idx;
}

__device__ inline unsigned short f2bf(float f) {   // RNE f32->bf16
  unsigned u = __float_as_uint(f);
  u += 0x7fffu + ((u >> 16) & 1u);
  return (unsigned short)(u >> 16);
}
__device__ inline float sigf(float x)      { return __builtin_amdgcn_rcpf(1.f + __expf(-x)); }
__device__ inline float tanh_fast(float x) { return 1.f - 2.f*__builtin_amdgcn_rcpf(1.f + __expf(2.f*x)); }

__device__ inline unsigned pk2(float a, float b) {   // v_cvt_pk_bf16_f32 (RNE)
  unsigned r;
  asm("v_cvt_pk_bf16_f32 %0, %1, %2" : "=v"(r) : "v"(a), "v"(b));
  return r;
}

// ---- cross-WG state ops: r3/r4/r5/r8-proven compiler-generated atomics.
// Exchange stores execute at the MALL; relaxed agent atomic loads read fresh.
__device__ inline void st_state_u64(unsigned short* p, unsigned long long v) {
  (void)__hip_atomic_exchange((unsigned long long*)p, v, __ATOMIC_RELAXED, __HIP_MEMORY_SCOPE_AGENT);
}
__device__ inline u32x4 ld_state_b128(const unsigned short* p) {
  unsigned long long* q = (unsigned long long*)p;
  unsigned long long s0 = __hip_atomic_load(q,     __ATOMIC_RELAXED, __HIP_MEMORY_SCOPE_AGENT);
  unsigned long long s1 = __hip_atomic_load(q + 1, __ATOMIC_RELAXED, __HIP_MEMORY_SCOPE_AGENT);
  u32x4 r;
  r.x = (unsigned)s0; r.y = (unsigned)(s0 >> 32);
  r.z = (unsigned)s1; r.w = (unsigned)(s1 >> 32);
  return r;
}

// Per-branch 32-flag barrier (r5/r8-proven machinery, halved fan-in, no fences).
// Flags are monotonic counters: stale polls only lengthen the spin.
__device__ inline void gbar_arrive(unsigned* fl, int w, unsigned phase) {
  asm volatile("s_waitcnt vmcnt(0)" ::: "memory");   // drain state exchanges first
  __syncthreads();
  if (threadIdx.x == 0)
    (void)__hip_atomic_exchange(fl + (size_t)w*16, phase, __ATOMIC_RELAXED, __HIP_MEMORY_SCOPE_AGENT);
}
__device__ inline unsigned mall_poll(const unsigned* p) {
  unsigned v;
  asm volatile("global_load_dword %0, %1, off sc0 sc1\n\ts_waitcnt vmcnt(0)"
               : "=&v"(v) : "v"(p) : "memory");
  return v;
}
__device__ inline void gbar_wait(unsigned* fl, unsigned phase) {
  if (threadIdx.x < 64) {
    unsigned* p = fl + (size_t)(threadIdx.x & 31)*16;
    int spins = 0;
    for (;;) {
      unsigned v = mall_poll(p);
      if (__all(v >= phase)) break;
      if (((++spins) & 255) == 255) {
        unsigned a = __hip_atomic_fetch_add(p, 0u, __ATOMIC_RELAXED, __HIP_MEMORY_SCOPE_AGENT);
        if (__all(a >= phase)) break;
      }
    }
  }
  __syncthreads();
  __builtin_amdgcn_sched_barrier(0);
}

// ======================= weight packing (fragment order) =======================
// frag elem index within a WG slice: ((mt*KT + kt)*64 + lane)*8 + e
// lane = lg*16 + ln holds row (mt*16+ln), k = kt*32 + lg*8 + e

__global__ __launch_bounds__(256) void k_pack_wc(const float* __restrict__ uW0, const float* __restrict__ lW0,
                                                 const float* __restrict__ linW, unsigned short* __restrict__ WAf) {
  int blk = blockIdx.x;                 // 2*1536 blocks
  int branch = blk / 1536, p = blk % 1536;
  const float* W0 = branch ? lW0 : uW0;
  int s = gate_src_row(p);
  int w = p / 48, rr = p % 48, mt = rr >> 4, ln = rr & 15;
  __shared__ float a[256];
  int tid = threadIdx.x;
  a[tid] = W0[(size_t)s*512 + tid];     // W0p row (cols 0:256 = prev-embed part)
  __syncthreads();
  size_t baseA = (((size_t)(branch*GW + w)*3 + mt)*24) * 64 * 8;
  for (int kk = 0; kk < 2; ++kk) {
    int k = kk*256 + tid;
    float acc = 0.f;
    #pragma unroll 8
    for (int e = 0; e < 256; ++e) acc = fmaf(a[e], linW[(size_t)e*512 + k], acc);
    int kt = k >> 5, lg = (k >> 3) & 3, e = k & 7;
    WAf[baseA + ((size_t)kt*64 + lg*16 + ln)*8 + e] = f2bf(acc);
  }
}

__global__ __launch_bounds__(256) void k_pack_rest(
    const float* __restrict__ uW0, const float* __restrict__ ubi0, const float* __restrict__ ubh0,
    const float* __restrict__ uW1, const float* __restrict__ ubi1, const float* __restrict__ ubh1,
    const float* __restrict__ lW0, const float* __restrict__ lbi0, const float* __restrict__ lbh0,
    const float* __restrict__ lW1, const float* __restrict__ lbi1, const float* __restrict__ lbh1,
    const float* __restrict__ linb,
    unsigned short* __restrict__ WAf, unsigned short* __restrict__ WBf,
    float* __restrict__ bA0, float* __restrict__ bA1, float* __restrict__ bBv) {
  int blk = blockIdx.x;
  int branch = blk / 1536, p = blk % 1536;
  const float* W0  = branch ? lW0  : uW0;
  const float* bi0 = branch ? lbi0 : ubi0;
  const float* bh0 = branch ? lbh0 : ubh0;
  const float* W1  = branch ? lW1  : uW1;
  const float* bi1 = branch ? lbi1 : ubi1;
  const float* bh1 = branch ? lbh1 : ubh1;
  int s = gate_src_row(p);
  int w = p / 48, rr = p % 48, mt = rr >> 4, ln = rr & 15;
  int tid = threadIdx.x;
  size_t baseA = (((size_t)(branch*GW + w)*3 + mt)*24) * 64 * 8;
  size_t baseB = (((size_t)(branch*GW + w)*3 + mt)*16) * 64 * 8;
  {  // W0f (feat part) -> kt 16..23
    int c = tid;
    int kt = 16 + (c >> 5), lg = (c >> 3) & 3, e = c & 7;
    WAf[baseA + ((size_t)kt*64 + lg*16 + ln)*8 + e] = f2bf(W0[(size_t)s*512 + 256 + c]);
  }
  for (int half = 0; half < 2; ++half) {
    int k = half*256 + tid;
    int kt = k >> 5, lg = (k >> 3) & 3, e = k & 7;
    WBf[baseB + ((size_t)kt*64 + lg*16 + ln)*8 + e] = f2bf(W1[(size_t)s*512 + k]);
  }
  __shared__ float red[256];
  red[tid] = W0[(size_t)s*512 + tid] * linb[tid];   // c0 = W0p @ lin_b
  __syncthreads();
  for (int st = 128; st > 0; st >>= 1) { if (tid < st) red[tid] += red[tid + st]; __syncthreads(); }
  if (tid == 0) {
    size_t rowA = (size_t)branch*1536 + p;
    float b0 = bi0[s] + bh0[s];
    bA0[rowA] = b0;
    bA1[rowA] = b0 + red[0];
    bBv[rowA] = bi1[s] + bh1[s];
  }
}

__global__ __launch_bounds__(256) void k_pack_wy(const float* __restrict__ linW, unsigned short* __restrict__ WYf) {
  int row = blockIdx.x;                 // 256 blocks
  int w2 = row >> 5, rr = row & 31, mt = rr >> 4, ln = rr & 15;
  int tid = threadIdx.x;
  size_t base = ((size_t)(w2*2 + mt)*16) * 64 * 8;
  for (int half = 0; half < 2; ++half) {
    int k = half*256 + tid;
    int kt = k >> 5, lg = (k >> 3) & 3, e = k & 7;
    WYf[base + ((size_t)kt*64 + lg*16 + ln)*8 + e] = f2bf(linW[(size_t)row*512 + k]);
  }
}

// ======================= persistent recurrent kernel =======================
// amdgpu_waves_per_eu(1,1): LDS (120KB, dynamic -> invisible to regalloc) already
// caps occupancy at 1 wave/SIMD; telling the allocator unlocks the full ~512-VGPR
// budget so the 32-load state batch (128 VGPRs) stays in flight (r5/r8/r9 showed
// VGPR 92-176 -> compiler serialized the loads chasing phantom occupancy).

__global__ __launch_bounds__(256) __attribute__((amdgpu_waves_per_eu(1, 1)))
void k_rnn(
    const float* __restrict__ featU, const float* __restrict__ featL,
    const float* __restrict__ linb,
    float* __restrict__ out, unsigned char* __restrict__ ws) {

  extern __shared__ unsigned char lds[];
  const int bid    = blockIdx.x;
  const int branch = bid / (GW + YW);
  const int role   = bid % (GW + YW);
  const bool isGate = role < GW;
  const int w = isGate ? role : (role - GW);
  const float* feat = branch ? featL : featU;

  const unsigned short* WAf = (const unsigned short*)(ws + OFF_WA);
  const unsigned short* WYf = (const unsigned short*)(ws + OFF_WY);
  const unsigned short* WBf = (const unsigned short*)(ws + OFF_WB);
  const float* bA0 = (const float*)(ws + OFF_BA0) + branch*1536;
  const float* bA1 = (const float*)(ws + OFF_BA1) + branch*1536;
  const float* bBv = (const float*)(ws + OFF_BBv) + branch*1536;
  unsigned short* xAr = (unsigned short*)(ws + OFF_XA);   // h1 slots [RROTA][2][...]
  unsigned short* xBr = (unsigned short*)(ws + OFF_XB);   // h0 slots [RROTB][2][...]
  unsigned* fl = (unsigned*)(ws + (branch ? OFF_FL1 : OFF_FL0));

  const int tid = threadIdx.x;
  const int l   = tid & 63;
  const int wv  = tid >> 6;   // wave 0..3
  const int lg  = l >> 4;     // k-subgroup 0..3
  const int ln  = l & 15;     // row/col in tile

  // ---- stage weights into LDS ----
  if (isGate) {
    const uint4* srcA = (const uint4*)(WAf + (size_t)(branch*GW + w)*36864);
    uint4* dA = (uint4*)lds;
    for (int i = tid; i < 4608; i += 256) dA[i] = srcA[i];
    const uint4* srcB = (const uint4*)(WBf + (size_t)(branch*GW + w)*24576);
    uint4* dB = (uint4*)(lds + 73728);
    for (int i = tid; i < 3072; i += 256) dB[i] = srcB[i];
  } else {
    const uint4* srcY = (const uint4*)(WYf + (size_t)w*16384);
    uint4* dY = (uint4*)lds;
    for (int i = tid; i < 2048; i += 256) dY[i] = srcY[i];
  }

  // ---- per-lane bias preload ----
  float ba0[12], ba1[12], bbv[12], by[8];
  if (isGate) {
    #pragma unroll
    for (int mt = 0; mt < 3; ++mt)
      #pragma unroll
      for (int rg = 0; rg < 4; ++rg) {
        int p = 48*w + mt*16 + 4*lg + rg;
        ba0[mt*4+rg] = bA0[p];
        ba1[mt*4+rg] = bA1[p];
        bbv[mt*4+rg] = bBv[p];
      }
  } else {
    #pragma unroll
    for (int mt = 0; mt < 2; ++mt)
      #pragma unroll
      for (int rg = 0; rg < 4; ++rg)
        by[mt*4+rg] = linb[32*w + mt*16 + 4*lg + rg];
  }
  __syncthreads();

  const f32x4 zv = {0.f, 0.f, 0.f, 0.f};

  if (isGate) {
    // featN: pre-accumulated feat-part of stage A for the NEXT timestep
    f32x4 featN[3][2];
    #pragma unroll
    for (int mt = 0; mt < 3; ++mt) { featN[mt][0] = zv; featN[mt][1] = zv; }

    auto featPart = [&](int lo, int hi, int tt) {
      for (int kt2 = lo; kt2 < hi; ++kt2) {
        short8 bfr[2];
        #pragma unroll
        for (int nt = 0; nt < 2; ++nt) {
          const int n = (wv*2 + nt)*16 + ln;
          const float* pf = feat + ((size_t)n*T_ + tt)*E_ + kt2*32 + 8*lg;
          float4 f0 = *(const float4*)pf;
          float4 f1 = *(const float4*)(pf + 4);
          u32x4 pk;
          pk.x = pk2(f0.x, f0.y); pk.y = pk2(f0.z, f0.w);
          pk.z = pk2(f1.x, f1.y); pk.w = pk2(f1.z, f1.w);
          bfr[nt] = __builtin_bit_cast(short8, pk);
        }
        #pragma unroll
        for (int mt = 0; mt < 3; ++mt) {
          short8 afr = *(const short8*)(lds + ((mt*24 + 16 + kt2)*64 + l)*16);
          #pragma unroll
          for (int nt = 0; nt < 2; ++nt)
            featN[mt][nt] = __builtin_amdgcn_mfma_f32_16x16x32_bf16(
                __builtin_bit_cast(bf16x8, afr), __builtin_bit_cast(bf16x8, bfr[nt]),
                featN[mt][nt], 0, 0, 0);
        }
      }
    };

    featPart(0, 8, 0);

    for (int t = 0; t < T_; ++t) {
      const unsigned short* xA_rd = xAr + ((size_t)((t-1) & (RROTA-1))*2 + branch)*B_*H_;
      unsigned short*       xB_wr = xBr + ((size_t)(t & (RROTB-1))*2 + branch)*B_*H_;
      const unsigned short* xB_rd = xB_wr;
      unsigned short*       xA_wr = xAr + ((size_t)(t & (RROTA-1))*2 + branch)*B_*H_;

      // ---------------- stage A: h0(t) = act(Wc@h1(t-1) + featN + bias) ----------------
      f32x4 acc[3][2];
      #pragma unroll
      for (int mt = 0; mt < 3; ++mt)
        #pragma unroll
        for (int nt = 0; nt < 2; ++nt) { acc[mt][nt] = featN[mt][nt]; featN[mt][nt] = zv; }

      if (t > 0) {
        gbar_wait(fl, 2u*t);                 // h1(t-1) at MALL
        u32x4 bs[2][16];                     // full batch: should now live in regs
        #pragma unroll
        for (int nt = 0; nt < 2; ++nt) {
          const int n = (wv*2 + nt)*16 + ln;
          const unsigned short* base = xA_rd + (size_t)n*32 + lg*8;
          #pragma unroll
          for (int kt = 0; kt < 16; ++kt)
            bs[nt][kt] = ld_state_b128(base + (size_t)kt*4096);
        }
        #pragma unroll
        for (int kt = 0; kt < 16; ++kt) {
          #pragma unroll
          for (int mt = 0; mt < 3; ++mt) {
            short8 afr = *(const short8*)(lds + ((mt*24 + kt)*64 + l)*16);
            #pragma unroll
            for (int nt = 0; nt < 2; ++nt)
              acc[mt][nt] = __builtin_amdgcn_mfma_f32_16x16x32_bf16(
                  __builtin_bit_cast(bf16x8, afr), __builtin_bit_cast(bf16x8, bs[nt][kt]),
                  acc[mt][nt], 0, 0, 0);
          }
        }
      }
      {
        float bcur[12];
        #pragma unroll
        for (int q = 0; q < 12; ++q) bcur[q] = (t == 0) ? ba0[q] : ba1[q];
        #pragma unroll
        for (int nt = 0; nt < 2; ++nt) {
          const int bcol = (wv*2 + nt)*16 + ln;
          unsigned long long hp[4];
          #pragma unroll
          for (int rg = 0; rg < 4; ++rg) {
            float iv = acc[0][nt][rg] + bcur[rg];
            float gv = acc[1][nt][rg] + bcur[4+rg];
            float ov = acc[2][nt][rg] + bcur[8+rg];
            float c  = sigf(iv) * tanh_fast(gv);
            float h  = sigf(ov) * tanh_fast(c);
            hp[rg] = (unsigned long long)f2bf(h);
          }
          unsigned long long v = hp[0] | (hp[1] << 16) | (hp[2] << 32) | (hp[3] << 48);
          st_state_u64(xB_wr + ((size_t)(w >> 1)*128 + bcol)*32 + (w & 1)*16 + lg*4, v);
        }
      }
      gbar_arrive(fl, w, 2u*t + 1);
      if (t + 1 < T_) featPart(0, 4, t + 1);   // hide barrier propagation
      gbar_wait(fl, 2u*t + 1);                 // h0(t) at MALL

      // ---------------- stage B: h1(t) = act(W1@h0(t) + bias) ----------------
      {
        u32x4 cs[2][16];
        #pragma unroll
        for (int nt = 0; nt < 2; ++nt) {
          const int n = (wv*2 + nt)*16 + ln;
          const unsigned short* base = xB_rd + (size_t)n*32 + lg*8;
          #pragma unroll
          for (int kt = 0; kt < 16; ++kt)
            cs[nt][kt] = ld_state_b128(base + (size_t)kt*4096);
        }
        f32x4 accB[3][2];
        #pragma unroll
        for (int mt = 0; mt < 3; ++mt) { accB[mt][0] = zv; accB[mt][1] = zv; }
        #pragma unroll
        for (int kt = 0; kt < 16; ++kt) {
          #pragma unroll
          for (int mt = 0; mt < 3; ++mt) {
            short8 afr = *(const short8*)(lds + 73728 + ((mt*16 + kt)*64 + l)*16);
            #pragma unroll
            for (int nt = 0; nt < 2; ++nt)
              accB[mt][nt] = __builtin_amdgcn_mfma_f32_16x16x32_bf16(
                  __builtin_bit_cast(bf16x8, afr), __builtin_bit_cast(bf16x8, cs[nt][kt]),
                  accB[mt][nt], 0, 0, 0);
          }
        }
        #pragma unroll
        for (int nt = 0; nt < 2; ++nt) {
          const int bcol = (wv*2 + nt)*16 + ln;
          unsigned long long hp[4];
          #pragma unroll
          for (int rg = 0; rg < 4; ++rg) {
            float iv = accB[0][nt][rg] + bbv[rg];
            float gv = accB[1][nt][rg] + bbv[4+rg];
            float ov = accB[2][nt][rg] + bbv[8+rg];
            float c  = sigf(iv) * tanh_fast(gv);
            float h  = sigf(ov) * tanh_fast(c);
            hp[rg] = (unsigned long long)f2bf(h);
          }
          unsigned long long v = hp[0] | (hp[1] << 16) | (hp[2] << 32) | (hp[3] << 48);
          st_state_u64(xA_wr + ((size_t)(w >> 1)*128 + bcol)*32 + (w & 1)*16 + lg*4, v);
        }
      }
      gbar_arrive(fl, w, 2u*t + 2);
      if (t + 1 < T_) featPart(4, 8, t + 1);   // hide barrier propagation
      // loop top does gbar_wait(2(t+1))
    }
  } else {
    // ==================== y WGs: decoupled consumers ====================
    // Never arrive; poll the gate flags (monotonic). h1(t-1) ready when all
    // flags >= 2t. RROTA=8 gives a 7-step overwrite cushion; y runs ~1 step
    // behind the gates (its per-step work is far smaller than a gate step).
    for (int t = 1; t <= T_; ++t) {
      gbar_wait(fl, 2u*t);
      const unsigned short* xA_rd = xAr + ((size_t)((t-1) & (RROTA-1))*2 + branch)*B_*H_;
      u32x4 bs[2][16];
      #pragma unroll
      for (int nt = 0; nt < 2; ++nt) {
        const int n = (wv*2 + nt)*16 + ln;
        const unsigned short* base = xA_rd + (size_t)n*32 + lg*8;
        #pragma unroll
        for (int kt = 0; kt < 16; ++kt)
          bs[nt][kt] = ld_state_b128(base + (size_t)kt*4096);
      }
      f32x4 acc[2][2];
      acc[0][0]=zv; acc[0][1]=zv; acc[1][0]=zv; acc[1][1]=zv;
      #pragma unroll
      for (int kt = 0; kt < 16; ++kt) {
        #pragma unroll
        for (int mt = 0; mt < 2; ++mt) {
          short8 afr = *(const short8*)(lds + ((mt*16 + kt)*64 + l)*16);
          #pragma unroll
          for (int nt = 0; nt < 2; ++nt)
            acc[mt][nt] = __builtin_amdgcn_mfma_f32_16x16x32_bf16(
                __builtin_bit_cast(bf16x8, afr), __builtin_bit_cast(bf16x8, bs[nt][kt]),
                acc[mt][nt], 0, 0, 0);
        }
      }
      #pragma unroll
      for (int mt = 0; mt < 2; ++mt)
        #pragma unroll
        for (int nt = 0; nt < 2; ++nt) {
          const int bcol = (wv*2 + nt)*16 + ln;
          float4 o;
          o.x = acc[mt][nt][0] + by[mt*4+0];
          o.y = acc[mt][nt][1] + by[mt*4+1];
          o.z = acc[mt][nt][2] + by[mt*4+2];
          o.w = acc[mt][nt][3] + by[mt*4+3];
          *(float4*)(out + (size_t)branch*TBE_ + ((size_t)(t-1)*B_ + bcol)*E_ + 32*w + mt*16 + 4*lg) = o;
        }
    }
  }
}

// ======================= launch =======================

extern "C" void kernel_launch(void* const* d_in, const int* in_sizes, int n_in,
                              void* d_out, int out_size, void* d_ws, size_t ws_size,
                              hipStream_t stream) {
  (void)in_sizes; (void)n_in; (void)out_size; (void)ws_size;
  const float* upF  = (const float*)d_in[0];
  const float* loF  = (const float*)d_in[1];
  const float* uW0  = (const float*)d_in[2];
  const float* ubi0 = (const float*)d_in[3];
  const float* ubh0 = (const float*)d_in[4];
  const float* uW1  = (const float*)d_in[5];
  const float* ubi1 = (const float*)d_in[6];
  const float* ubh1 = (const float*)d_in[7];
  const float* lW0  = (const float*)d_in[8];
  const float* lbi0 = (const float*)d_in[9];
  const float* lbh0 = (const float*)d_in[10];
  const float* lW1  = (const float*)d_in[11];
  const float* lbi1 = (const float*)d_in[12];
  const float* lbh1 = (const float*)d_in[13];
  const float* linW = (const float*)d_in[14];
  const float* linb = (const float*)d_in[15];
  float* out = (float*)d_out;
  unsigned char* ws = (unsigned char*)d_ws;

  unsigned short* WAf = (unsigned short*)(ws + OFF_WA);
  unsigned short* WYf = (unsigned short*)(ws + OFF_WY);
  unsigned short* WBf = (unsigned short*)(ws + OFF_WB);
  float* bA0 = (float*)(ws + OFF_BA0);
  float* bA1 = (float*)(ws + OFF_BA1);
  float* bBv = (float*)(ws + OFF_BBv);

  hipMemsetAsync(d_ws, 0, 8192, stream);   // zero per-branch flag arrays

  k_pack_wc<<<dim3(2*1536), dim3(256), 0, stream>>>(uW0, lW0, linW, WAf);
  k_pack_rest<<<dim3(2*1536), dim3(256), 0, stream>>>(uW0, ubi0, ubh0, uW1, ubi1, ubh1,
                                                      lW0, lbi0, lbh0, lW1, lbi1, lbh1,
                                                      linb, WAf, WBf, bA0, bA1, bBv);
  k_pack_wy<<<dim3(256), dim3(256), 0, stream>>>(linW, WYf);

  hipFuncSetAttribute((const void*)k_rnn, hipFuncAttributeMaxDynamicSharedMemorySize, LDS_BYTES);
  k_rnn<<<dim3(NWG), dim3(256), LDS_BYTES, stream>>>(upF, loF, linb, out, ws);
}

// Round 13
// 4601.377 us; speedup vs baseline: 4.3416x; 1.8220x over previous
//
#include <hip/hip_runtime.h>
#include <hip/hip_bf16.h>

// Problem constants
#define E_   256
#define H_   512
#define T_   512
#define B_   128
#define TBE_ (T_*B_*E_)

#define GW 32               // gate WGs per sync domain (branch x batch-half)
#define YW 8                // y WGs per branch
#define NWG 144             // 2br x 2half x 32 gates + 2br x 8 y
#define RROTA 8             // h1 rotation (y reads with lag cushion)
#define RROTB 4             // h0 rotation
#define LDS_BYTES 122880    // 73728 (stage-A frags) + 49152 (stage-B frags)

typedef __attribute__((ext_vector_type(4))) float  f32x4;
typedef __attribute__((ext_vector_type(8))) __bf16 bf16x8;
typedef __attribute__((ext_vector_type(8))) short  short8;
typedef __attribute__((ext_vector_type(4))) unsigned int u32x4;

// ---- workspace layout (bytes) ----
// flags: [branch][half][32 x 64B] = 4 x 2048 at ws+0 (memset 8192 covers)
#define OFF_WA   8192                          // stage-A frag weights [2][32][3][24][64][8] bf16
#define SZ_WA    (2*GW*3*24*64*8*2)            // 4,718,592
#define OFF_WY   (OFF_WA + SZ_WA)              // y frag weights
#define SZ_WY    (YW*2*16*64*8*2)              // 262,144
#define OFF_WB   (OFF_WY + SZ_WY)              // stage-B frag weights
#define SZ_WB    (2*GW*3*16*64*8*2)            // 3,145,728
#define OFF_BA0  (OFF_WB + SZ_WB)
#define OFF_BA1  (OFF_BA0 + 2*1536*4)
#define OFF_BBv  (OFF_BA1 + 2*1536*4)
#define OFF_XA   (OFF_BBv + 2*1536*4)          // h1 state [RROTA][2][16][128][32] bf16
#define SZ_XA    (RROTA*2*B_*H_*2)             // 2,097,152
#define OFF_XB   (OFF_XA + SZ_XA)              // h0 state [RROTB][2][...]
#define SZ_XB    (RROTB*2*B_*H_*2)             // 1,048,576
#define WS_NEED  (OFF_XB + SZ_XB)              // ~11.4 MB

__device__ __host__ inline int gate_src_row(int p) {
  // packed row p in [0,1536): w=p/48 slice, r=p%48: [0,16)=i, [16,32)=g, [32,48)=o
  int w = p / 48, r = p % 48;
  int grp = r >> 4;
  int idx = r & 15;
  int base = (grp == 0) ? 0 : (grp == 1 ? 1024 : 1536);
  return base + 16*w + idx;
}

__device__ inline unsigned short f2bf(float f) {   // RNE f32->bf16
  unsigned u = __float_as_uint(f);
  u += 0x7fffu + ((u >> 16) & 1u);
  return (unsigned short)(u >> 16);
}
__device__ inline float sigf(float x)      { return __builtin_amdgcn_rcpf(1.f + __expf(-x)); }
__device__ inline float tanh_fast(float x) { return 1.f - 2.f*__builtin_amdgcn_rcpf(1.f + __expf(2.f*x)); }

__device__ inline unsigned pk2(float a, float b) {   // v_cvt_pk_bf16_f32 (RNE)
  unsigned r;
  asm("v_cvt_pk_bf16_f32 %0, %1, %2" : "=v"(r) : "v"(a), "v"(b));
  return r;
}

// ---- cross-WG state ops: r3/r4/r5/r8/r12-proven compiler-generated atomics.
__device__ inline void st_state_u64(unsigned short* p, unsigned long long v) {
  (void)__hip_atomic_exchange((unsigned long long*)p, v, __ATOMIC_RELAXED, __HIP_MEMORY_SCOPE_AGENT);
}
__device__ inline u32x4 ld_state_b128(const unsigned short* p) {
  unsigned long long* q = (unsigned long long*)p;
  unsigned long long s0 = __hip_atomic_load(q,     __ATOMIC_RELAXED, __HIP_MEMORY_SCOPE_AGENT);
  unsigned long long s1 = __hip_atomic_load(q + 1, __ATOMIC_RELAXED, __HIP_MEMORY_SCOPE_AGENT);
  u32x4 r;
  r.x = (unsigned)s0; r.y = (unsigned)(s0 >> 32);
  r.z = (unsigned)s1; r.w = (unsigned)(s1 >> 32);
  return r;
}

// Per-domain 32-flag barrier (proven machinery). Monotonic flags: stale polls
// only lengthen the spin.
__device__ inline void gbar_arrive(unsigned* fl, int w, unsigned phase) {
  asm volatile("s_waitcnt vmcnt(0)" ::: "memory");   // drain state exchanges first
  __syncthreads();
  if (threadIdx.x == 0)
    (void)__hip_atomic_exchange(fl + (size_t)w*16, phase, __ATOMIC_RELAXED, __HIP_MEMORY_SCOPE_AGENT);
}
__device__ inline unsigned mall_poll(const unsigned* p) {
  unsigned v;
  asm volatile("global_load_dword %0, %1, off sc0 sc1\n\ts_waitcnt vmcnt(0)"
               : "=&v"(v) : "v"(p) : "memory");
  return v;
}
__device__ inline void poll2(const unsigned* p0, const unsigned* p1, unsigned& a, unsigned& b) {
  asm volatile("global_load_dword %0, %2, off sc0 sc1\n\t"
               "global_load_dword %1, %3, off sc0 sc1\n\t"
               "s_waitcnt vmcnt(0)"
               : "=&v"(a), "=&v"(b) : "v"(p0), "v"(p1) : "memory");
}
__device__ inline void gbar_wait(unsigned* fl, unsigned phase) {
  if (threadIdx.x < 64) {
    unsigned* p = fl + (size_t)(threadIdx.x & 31)*16;
    int spins = 0;
    for (;;) {
      unsigned v = mall_poll(p);
      if (__all(v >= phase)) break;
      if (((++spins) & 255) == 255) {
        unsigned a = __hip_atomic_fetch_add(p, 0u, __ATOMIC_RELAXED, __HIP_MEMORY_SCOPE_AGENT);
        if (__all(a >= phase)) break;
      }
    }
  }
  __syncthreads();
  __builtin_amdgcn_sched_barrier(0);
}
__device__ inline void ybar_wait2(unsigned* flA, unsigned* flB, unsigned phase) {
  if (threadIdx.x < 64) {
    unsigned* p0 = flA + (size_t)(threadIdx.x & 31)*16;
    unsigned* p1 = flB + (size_t)(threadIdx.x & 31)*16;
    int spins = 0;
    for (;;) {
      unsigned a, b;
      poll2(p0, p1, a, b);
      if (__all((a >= phase) && (b >= phase))) break;
      if (((++spins) & 255) == 255) {
        a = __hip_atomic_fetch_add(p0, 0u, __ATOMIC_RELAXED, __HIP_MEMORY_SCOPE_AGENT);
        b = __hip_atomic_fetch_add(p1, 0u, __ATOMIC_RELAXED, __HIP_MEMORY_SCOPE_AGENT);
        if (__all((a >= phase) && (b >= phase))) break;
      }
    }
  }
  __syncthreads();
  __builtin_amdgcn_sched_barrier(0);
}

// ======================= weight packing (fragment order) =======================
// frag elem index within a WG slice: ((mt*KT + kt)*64 + lane)*8 + e
// lane = lg*16 + ln holds row (mt*16+ln), k = kt*32 + lg*8 + e

__global__ __launch_bounds__(256) void k_pack_wc(const float* __restrict__ uW0, const float* __restrict__ lW0,
                                                 const float* __restrict__ linW, unsigned short* __restrict__ WAf) {
  int blk = blockIdx.x;                 // 2*1536 blocks
  int branch = blk / 1536, p = blk % 1536;
  const float* W0 = branch ? lW0 : uW0;
  int s = gate_src_row(p);
  int w = p / 48, rr = p % 48, mt = rr >> 4, ln = rr & 15;
  __shared__ float a[256];
  int tid = threadIdx.x;
  a[tid] = W0[(size_t)s*512 + tid];     // W0p row (cols 0:256 = prev-embed part)
  __syncthreads();
  size_t baseA = (((size_t)(branch*GW + w)*3 + mt)*24) * 64 * 8;
  for (int kk = 0; kk < 2; ++kk) {
    int k = kk*256 + tid;
    float acc = 0.f;
    #pragma unroll 8
    for (int e = 0; e < 256; ++e) acc = fmaf(a[e], linW[(size_t)e*512 + k], acc);
    int kt = k >> 5, lg = (k >> 3) & 3, e = k & 7;
    WAf[baseA + ((size_t)kt*64 + lg*16 + ln)*8 + e] = f2bf(acc);
  }
}

__global__ __launch_bounds__(256) void k_pack_rest(
    const float* __restrict__ uW0, const float* __restrict__ ubi0, const float* __restrict__ ubh0,
    const float* __restrict__ uW1, const float* __restrict__ ubi1, const float* __restrict__ ubh1,
    const float* __restrict__ lW0, const float* __restrict__ lbi0, const float* __restrict__ lbh0,
    const float* __restrict__ lW1, const float* __restrict__ lbi1, const float* __restrict__ lbh1,
    const float* __restrict__ linb,
    unsigned short* __restrict__ WAf, unsigned short* __restrict__ WBf,
    float* __restrict__ bA0, float* __restrict__ bA1, float* __restrict__ bBv) {
  int blk = blockIdx.x;
  int branch = blk / 1536, p = blk % 1536;
  const float* W0  = branch ? lW0  : uW0;
  const float* bi0 = branch ? lbi0 : ubi0;
  const float* bh0 = branch ? lbh0 : ubh0;
  const float* W1  = branch ? lW1  : uW1;
  const float* bi1 = branch ? lbi1 : ubi1;
  const float* bh1 = branch ? lbh1 : ubh1;
  int s = gate_src_row(p);
  int w = p / 48, rr = p % 48, mt = rr >> 4, ln = rr & 15;
  int tid = threadIdx.x;
  size_t baseA = (((size_t)(branch*GW + w)*3 + mt)*24) * 64 * 8;
  size_t baseB = (((size_t)(branch*GW + w)*3 + mt)*16) * 64 * 8;
  {  // W0f (feat part) -> kt 16..23
    int c = tid;
    int kt = 16 + (c >> 5), lg = (c >> 3) & 3, e = c & 7;
    WAf[baseA + ((size_t)kt*64 + lg*16 + ln)*8 + e] = f2bf(W0[(size_t)s*512 + 256 + c]);
  }
  for (int half = 0; half < 2; ++half) {
    int k = half*256 + tid;
    int kt = k >> 5, lg = (k >> 3) & 3, e = k & 7;
    WBf[baseB + ((size_t)kt*64 + lg*16 + ln)*8 + e] = f2bf(W1[(size_t)s*512 + k]);
  }
  __shared__ float red[256];
  red[tid] = W0[(size_t)s*512 + tid] * linb[tid];   // c0 = W0p @ lin_b
  __syncthreads();
  for (int st = 128; st > 0; st >>= 1) { if (tid < st) red[tid] += red[tid + st]; __syncthreads(); }
  if (tid == 0) {
    size_t rowA = (size_t)branch*1536 + p;
    float b0 = bi0[s] + bh0[s];
    bA0[rowA] = b0;
    bA1[rowA] = b0 + red[0];
    bBv[rowA] = bi1[s] + bh1[s];
  }
}

__global__ __launch_bounds__(256) void k_pack_wy(const float* __restrict__ linW, unsigned short* __restrict__ WYf) {
  int row = blockIdx.x;                 // 256 blocks
  int w2 = row >> 5, rr = row & 31, mt = rr >> 4, ln = rr & 15;
  int tid = threadIdx.x;
  size_t base = ((size_t)(w2*2 + mt)*16) * 64 * 8;
  for (int half = 0; half < 2; ++half) {
    int k = half*256 + tid;
    int kt = k >> 5, lg = (k >> 3) & 3, e = k & 7;
    WYf[base + ((size_t)kt*64 + lg*16 + ln)*8 + e] = f2bf(linW[(size_t)row*512 + k]);
  }
}

// ======================= persistent recurrent kernel =======================

__global__ __launch_bounds__(256, 1) void k_rnn(
    const float* __restrict__ featU, const float* __restrict__ featL,
    const float* __restrict__ linb,
    float* __restrict__ out, unsigned char* __restrict__ ws) {

  extern __shared__ unsigned char lds[];
  const int bid = blockIdx.x;
  const bool isGate = bid < 128;
  const int branch = isGate ? (bid >> 6) : ((bid - 128) >> 3);
  const int half   = isGate ? ((bid >> 5) & 1) : 0;
  const int w      = isGate ? (bid & 31) : ((bid - 128) & 7);
  const float* feat = branch ? featL : featU;

  const unsigned short* WAf = (const unsigned short*)(ws + OFF_WA);
  const unsigned short* WYf = (const unsigned short*)(ws + OFF_WY);
  const unsigned short* WBf = (const unsigned short*)(ws + OFF_WB);
  const float* bA0 = (const float*)(ws + OFF_BA0) + branch*1536;
  const float* bA1 = (const float*)(ws + OFF_BA1) + branch*1536;
  const float* bBv = (const float*)(ws + OFF_BBv) + branch*1536;
  unsigned short* xAr = (unsigned short*)(ws + OFF_XA);   // h1 slots [RROTA][2][...]
  unsigned short* xBr = (unsigned short*)(ws + OFF_XB);   // h0 slots [RROTB][2][...]
  unsigned* fl  = (unsigned*)(ws + (size_t)(branch*2 + half)*2048);   // own domain
  unsigned* fl0 = (unsigned*)(ws + (size_t)(branch*2 + 0)*2048);      // y: both halves
  unsigned* fl1 = (unsigned*)(ws + (size_t)(branch*2 + 1)*2048);

  const int tid = threadIdx.x;
  const int l   = tid & 63;
  const int wv  = tid >> 6;   // wave 0..3
  const int lg  = l >> 4;     // k-subgroup 0..3
  const int ln  = l & 15;     // row/col in tile

  // ---- stage weights into LDS ----
  if (isGate) {
    const uint4* srcA = (const uint4*)(WAf + (size_t)(branch*GW + w)*36864);
    uint4* dA = (uint4*)lds;
    for (int i = tid; i < 4608; i += 256) dA[i] = srcA[i];
    const uint4* srcB = (const uint4*)(WBf + (size_t)(branch*GW + w)*24576);
    uint4* dB = (uint4*)(lds + 73728);
    for (int i = tid; i < 3072; i += 256) dB[i] = srcB[i];
  } else {
    const uint4* srcY = (const uint4*)(WYf + (size_t)w*16384);
    uint4* dY = (uint4*)lds;
    for (int i = tid; i < 2048; i += 256) dY[i] = srcY[i];
  }

  // ---- per-lane bias preload ----
  float ba0[12], ba1[12], bbv[12], by[8];
  if (isGate) {
    #pragma unroll
    for (int mt = 0; mt < 3; ++mt)
      #pragma unroll
      for (int rg = 0; rg < 4; ++rg) {
        int p = 48*w + mt*16 + 4*lg + rg;
        ba0[mt*4+rg] = bA0[p];
        ba1[mt*4+rg] = bA1[p];
        bbv[mt*4+rg] = bBv[p];
      }
  } else {
    #pragma unroll
    for (int mt = 0; mt < 2; ++mt)
      #pragma unroll
      for (int rg = 0; rg < 4; ++rg)
        by[mt*4+rg] = linb[32*w + mt*16 + 4*lg + rg];
  }
  __syncthreads();

  const f32x4 zv = {0.f, 0.f, 0.f, 0.f};

  if (isGate) {
    const int n = 64*half + wv*16 + ln;   // this thread's batch column (fixed)

    // featN: pre-accumulated feat-part of stage A for the NEXT timestep
    f32x4 featN[3];
    #pragma unroll
    for (int mt = 0; mt < 3; ++mt) featN[mt] = zv;

    auto featPart = [&](int lo, int hi, int tt) {
      for (int kt2 = lo; kt2 < hi; ++kt2) {
        const float* pf = feat + ((size_t)n*T_ + tt)*E_ + kt2*32 + 8*lg;
        float4 f0 = *(const float4*)pf;
        float4 f1 = *(const float4*)(pf + 4);
        u32x4 pk;
        pk.x = pk2(f0.x, f0.y); pk.y = pk2(f0.z, f0.w);
        pk.z = pk2(f1.x, f1.y); pk.w = pk2(f1.z, f1.w);
        short8 bfr = __builtin_bit_cast(short8, pk);
        #pragma unroll
        for (int mt = 0; mt < 3; ++mt) {
          short8 afr = *(const short8*)(lds + ((mt*24 + 16 + kt2)*64 + l)*16);
          featN[mt] = __builtin_amdgcn_mfma_f32_16x16x32_bf16(
              __builtin_bit_cast(bf16x8, afr), __builtin_bit_cast(bf16x8, bfr),
              featN[mt], 0, 0, 0);
        }
      }
    };

    featPart(0, 8, 0);

    for (int t = 0; t < T_; ++t) {
      const unsigned short* xA_rd = xAr + ((size_t)((t-1) & (RROTA-1))*2 + branch)*B_*H_;
      unsigned short*       xB_wr = xBr + ((size_t)(t & (RROTB-1))*2 + branch)*B_*H_;
      const unsigned short* xB_rd = xB_wr;
      unsigned short*       xA_wr = xAr + ((size_t)(t & (RROTA-1))*2 + branch)*B_*H_;

      // ---------------- stage A: h0(t) = act(Wc@h1(t-1) + featN + bias) ----------------
      f32x4 acc[3];
      #pragma unroll
      for (int mt = 0; mt < 3; ++mt) { acc[mt] = featN[mt]; featN[mt] = zv; }

      if (t > 0) {
        gbar_wait(fl, 2u*t);                 // h1(t-1) visible
        const unsigned short* base = xA_rd + (size_t)n*32 + lg*8;
        u32x4 bs[16];                        // 64 VGPRs: chunked pipeline (r8 pattern)
        #pragma unroll
        for (int kt = 0; kt < 8; ++kt) bs[kt] = ld_state_b128(base + (size_t)kt*4096);
        __builtin_amdgcn_sched_barrier(0);
        #pragma unroll
        for (int c = 0; c < 4; ++c) {
          if (c < 2) {
            #pragma unroll
            for (int kt = 8 + 4*c; kt < 12 + 4*c; ++kt)
              bs[kt] = ld_state_b128(base + (size_t)kt*4096);
            __builtin_amdgcn_sched_barrier(0);
          }
          #pragma unroll
          for (int kt = 4*c; kt < 4*c + 4; ++kt) {
            #pragma unroll
            for (int mt = 0; mt < 3; ++mt) {
              short8 afr = *(const short8*)(lds + ((mt*24 + kt)*64 + l)*16);
              acc[mt] = __builtin_amdgcn_mfma_f32_16x16x32_bf16(
                  __builtin_bit_cast(bf16x8, afr), __builtin_bit_cast(bf16x8, bs[kt]),
                  acc[mt], 0, 0, 0);
            }
          }
          __builtin_amdgcn_sched_barrier(0);
        }
      }
      {
        float bcur[12];
        #pragma unroll
        for (int q = 0; q < 12; ++q) bcur[q] = (t == 0) ? ba0[q] : ba1[q];
        unsigned long long hp[4];
        #pragma unroll
        for (int rg = 0; rg < 4; ++rg) {
          float iv = acc[0][rg] + bcur[rg];
          float gv = acc[1][rg] + bcur[4+rg];
          float ov = acc[2][rg] + bcur[8+rg];
          float c  = sigf(iv) * tanh_fast(gv);
          float h  = sigf(ov) * tanh_fast(c);
          hp[rg] = (unsigned long long)f2bf(h);
        }
        unsigned long long v = hp[0] | (hp[1] << 16) | (hp[2] << 32) | (hp[3] << 48);
        st_state_u64(xB_wr + ((size_t)(w >> 1)*128 + n)*32 + (w & 1)*16 + lg*4, v);
      }
      gbar_arrive(fl, w, 2u*t + 1);
      if (t + 1 < T_) featPart(0, 4, t + 1);   // hide barrier propagation
      gbar_wait(fl, 2u*t + 1);                 // h0(t) visible

      // ---------------- stage B: h1(t) = act(W1@h0(t) + bias) ----------------
      {
        const unsigned short* base = xB_rd + (size_t)n*32 + lg*8;
        u32x4 cs[16];
        #pragma unroll
        for (int kt = 0; kt < 8; ++kt) cs[kt] = ld_state_b128(base + (size_t)kt*4096);
        __builtin_amdgcn_sched_barrier(0);
        f32x4 accB[3];
        #pragma unroll
        for (int mt = 0; mt < 3; ++mt) accB[mt] = zv;
        #pragma unroll
        for (int c = 0; c < 4; ++c) {
          if (c < 2) {
            #pragma unroll
            for (int kt = 8 + 4*c; kt < 12 + 4*c; ++kt)
              cs[kt] = ld_state_b128(base + (size_t)kt*4096);
            __builtin_amdgcn_sched_barrier(0);
          }
          #pragma unroll
          for (int kt = 4*c; kt < 4*c + 4; ++kt) {
            #pragma unroll
            for (int mt = 0; mt < 3; ++mt) {
              short8 afr = *(const short8*)(lds + 73728 + ((mt*16 + kt)*64 + l)*16);
              accB[mt] = __builtin_amdgcn_mfma_f32_16x16x32_bf16(
                  __builtin_bit_cast(bf16x8, afr), __builtin_bit_cast(bf16x8, cs[kt]),
                  accB[mt], 0, 0, 0);
            }
          }
          __builtin_amdgcn_sched_barrier(0);
        }
        unsigned long long hp[4];
        #pragma unroll
        for (int rg = 0; rg < 4; ++rg) {
          float iv = accB[0][rg] + bbv[rg];
          float gv = accB[1][rg] + bbv[4+rg];
          float ov = accB[2][rg] + bbv[8+rg];
          float c  = sigf(iv) * tanh_fast(gv);
          float h  = sigf(ov) * tanh_fast(c);
          hp[rg] = (unsigned long long)f2bf(h);
        }
        unsigned long long v = hp[0] | (hp[1] << 16) | (hp[2] << 32) | (hp[3] << 48);
        st_state_u64(xA_wr + ((size_t)(w >> 1)*128 + n)*32 + (w & 1)*16 + lg*4, v);
      }
      gbar_arrive(fl, w, 2u*t + 2);
      if (t + 1 < T_) featPart(4, 8, t + 1);   // hide barrier propagation
      // loop top does gbar_wait(2(t+1))
    }
  } else {
    // ==================== y WGs: decoupled consumers (full batch) ====================
    for (int t = 1; t <= T_; ++t) {
      ybar_wait2(fl0, fl1, 2u*t);            // both halves' h1(t-1) visible
      const unsigned short* xA_rd = xAr + ((size_t)((t-1) & (RROTA-1))*2 + branch)*B_*H_;
      u32x4 bs[2][16];
      #pragma unroll
      for (int nt = 0; nt < 2; ++nt) {
        const int nn = (wv*2 + nt)*16 + ln;
        const unsigned short* base = xA_rd + (size_t)nn*32 + lg*8;
        #pragma unroll
        for (int kt = 0; kt < 16; ++kt)
          bs[nt][kt] = ld_state_b128(base + (size_t)kt*4096);
      }
      f32x4 acc[2][2];
      acc[0][0]=zv; acc[0][1]=zv; acc[1][0]=zv; acc[1][1]=zv;
      #pragma unroll
      for (int kt = 0; kt < 16; ++kt) {
        #pragma unroll
        for (int mt = 0; mt < 2; ++mt) {
          short8 afr = *(const short8*)(lds + ((mt*16 + kt)*64 + l)*16);
          #pragma unroll
          for (int nt = 0; nt < 2; ++nt)
            acc[mt][nt] = __builtin_amdgcn_mfma_f32_16x16x32_bf16(
                __builtin_bit_cast(bf16x8, afr), __builtin_bit_cast(bf16x8, bs[nt][kt]),
                acc[mt][nt], 0, 0, 0);
        }
      }
      #pragma unroll
      for (int mt = 0; mt < 2; ++mt)
        #pragma unroll
        for (int nt = 0; nt < 2; ++nt) {
          const int bcol = (wv*2 + nt)*16 + ln;
          float4 o;
          o.x = acc[mt][nt][0] + by[mt*4+0];
          o.y = acc[mt][nt][1] + by[mt*4+1];
          o.z = acc[mt][nt][2] + by[mt*4+2];
          o.w = acc[mt][nt][3] + by[mt*4+3];
          *(float4*)(out + (size_t)branch*TBE_ + ((size_t)(t-1)*B_ + bcol)*E_ + 32*w + mt*16 + 4*lg) = o;
        }
    }
  }
}

// ======================= launch =======================

extern "C" void kernel_launch(void* const* d_in, const int* in_sizes, int n_in,
                              void* d_out, int out_size, void* d_ws, size_t ws_size,
                              hipStream_t stream) {
  (void)in_sizes; (void)n_in; (void)out_size; (void)ws_size;
  const float* upF  = (const float*)d_in[0];
  const float* loF  = (const float*)d_in[1];
  const float* uW0  = (const float*)d_in[2];
  const float* ubi0 = (const float*)d_in[3];
  const float* ubh0 = (const float*)d_in[4];
  const float* uW1  = (const float*)d_in[5];
  const float* ubi1 = (const float*)d_in[6];
  const float* ubh1 = (const float*)d_in[7];
  const float* lW0  = (const float*)d_in[8];
  const float* lbi0 = (const float*)d_in[9];
  const float* lbh0 = (const float*)d_in[10];
  const float* lW1  = (const float*)d_in[11];
  const float* lbi1 = (const float*)d_in[12];
  const float* lbh1 = (const float*)d_in[13];
  const float* linW = (const float*)d_in[14];
  const float* linb = (const float*)d_in[15];
  float* out = (float*)d_out;
  unsigned char* ws = (unsigned char*)d_ws;

  unsigned short* WAf = (unsigned short*)(ws + OFF_WA);
  unsigned short* WYf = (unsigned short*)(ws + OFF_WY);
  unsigned short* WBf = (unsigned short*)(ws + OFF_WB);
  float* bA0 = (float*)(ws + OFF_BA0);
  float* bA1 = (float*)(ws + OFF_BA1);
  float* bBv = (float*)(ws + OFF_BBv);

  hipMemsetAsync(d_ws, 0, 8192, stream);   // zero the 4 flag domains

  k_pack_wc<<<dim3(2*1536), dim3(256), 0, stream>>>(uW0, lW0, linW, WAf);
  k_pack_rest<<<dim3(2*1536), dim3(256), 0, stream>>>(uW0, ubi0, ubh0, uW1, ubi1, ubh1,
                                                      lW0, lbi0, lbh0, lW1, lbi1, lbh1,
                                                      linb, WAf, WBf, bA0, bA1, bBv);
  k_pack_wy<<<dim3(256), dim3(256), 0, stream>>>(linW, WYf);

  hipFuncSetAttribute((const void*)k_rnn, hipFuncAttributeMaxDynamicSharedMemorySize, LDS_BYTES);
  k_rnn<<<dim3(NWG), dim3(256), LDS_BYTES, stream>>>(upF, loF, linb, out, ws);
}

// Round 14
// 4519.264 us; speedup vs baseline: 4.4204x; 1.0182x over previous
//
#include <hip/hip_runtime.h>
#include <hip/hip_bf16.h>

// Problem constants
#define E_   256
#define H_   512
#define T_   512
#define B_   128
#define TBE_ (T_*B_*E_)

#define GW 32               // gate WGs per sync domain (branch x batch-half)
#define YW 8                // y WGs per branch
#define NWG 144             // 2br x 2half x 32 gates + 2br x 8 y
#define RROTA 8             // h1 rotation (y reads with lag cushion)
#define RROTB 4             // h0 rotation
#define LDS_BYTES 122880    // 73728 (stage-A frags) + 49152 (stage-B frags)

typedef __attribute__((ext_vector_type(4))) float  f32x4;
typedef __attribute__((ext_vector_type(8))) __bf16 bf16x8;
typedef __attribute__((ext_vector_type(8))) short  short8;
typedef __attribute__((ext_vector_type(4))) unsigned int u32x4;

// ---- workspace layout (bytes) ----
// flags: [branch][half][32 x 64B] = 4 x 2048 at ws+0 (memset 8192 covers)
#define OFF_WA   8192                          // stage-A frag weights [2][32][3][24][64][8] bf16
#define SZ_WA    (2*GW*3*24*64*8*2)            // 4,718,592
#define OFF_WY   (OFF_WA + SZ_WA)              // y frag weights
#define SZ_WY    (YW*2*16*64*8*2)              // 262,144
#define OFF_WB   (OFF_WY + SZ_WY)              // stage-B frag weights
#define SZ_WB    (2*GW*3*16*64*8*2)            // 3,145,728
#define OFF_BA0  (OFF_WB + SZ_WB)
#define OFF_BA1  (OFF_BA0 + 2*1536*4)
#define OFF_BBv  (OFF_BA1 + 2*1536*4)
#define OFF_XA   (OFF_BBv + 2*1536*4)          // h1 state [RROTA][2][16][128][32] bf16
#define SZ_XA    (RROTA*2*B_*H_*2)             // 2,097,152
#define OFF_XB   (OFF_XA + SZ_XA)              // h0 state [RROTB][2][...]
#define SZ_XB    (RROTB*2*B_*H_*2)             // 1,048,576
#define WS_NEED  (OFF_XB + SZ_XB)              // ~11.4 MB

__device__ __host__ inline int gate_src_row(int p) {
  // packed row p in [0,1536): w=p/48 slice, r=p%48: [0,16)=i, [16,32)=g, [32,48)=o
  int w = p / 48, r = p % 48;
  int grp = r >> 4;
  int idx = r & 15;
  int base = (grp == 0) ? 0 : (grp == 1 ? 1024 : 1536);
  return base + 16*w + idx;
}

__device__ inline unsigned short f2bf(float f) {   // RNE f32->bf16
  unsigned u = __float_as_uint(f);
  u += 0x7fffu + ((u >> 16) & 1u);
  return (unsigned short)(u >> 16);
}
__device__ inline float sigf(float x)      { return __builtin_amdgcn_rcpf(1.f + __expf(-x)); }
__device__ inline float tanh_fast(float x) { return 1.f - 2.f*__builtin_amdgcn_rcpf(1.f + __expf(2.f*x)); }

__device__ inline unsigned pk2(float a, float b) {   // v_cvt_pk_bf16_f32 (RNE)
  unsigned r;
  asm("v_cvt_pk_bf16_f32 %0, %1, %2" : "=v"(r) : "v"(a), "v"(b));
  return r;
}

// ---- cross-WG state ops: r3-r13-proven compiler-generated atomics.
__device__ inline void st_state_u64(unsigned short* p, unsigned long long v) {
  (void)__hip_atomic_exchange((unsigned long long*)p, v, __ATOMIC_RELAXED, __HIP_MEMORY_SCOPE_AGENT);
}
__device__ inline u32x4 ld_state_b128(const unsigned short* p) {
  unsigned long long* q = (unsigned long long*)p;
  unsigned long long s0 = __hip_atomic_load(q,     __ATOMIC_RELAXED, __HIP_MEMORY_SCOPE_AGENT);
  unsigned long long s1 = __hip_atomic_load(q + 1, __ATOMIC_RELAXED, __HIP_MEMORY_SCOPE_AGENT);
  u32x4 r;
  r.x = (unsigned)s0; r.y = (unsigned)(s0 >> 32);
  r.z = (unsigned)s1; r.w = (unsigned)(s1 >> 32);
  return r;
}

// Per-domain 32-flag barrier (proven machinery). Monotonic flags: stale polls
// only lengthen the spin.
__device__ inline void gbar_arrive(unsigned* fl, int w, unsigned phase) {
  asm volatile("s_waitcnt vmcnt(0)" ::: "memory");   // drain state exchanges first
  __syncthreads();
  if (threadIdx.x == 0)
    (void)__hip_atomic_exchange(fl + (size_t)w*16, phase, __ATOMIC_RELAXED, __HIP_MEMORY_SCOPE_AGENT);
}
__device__ inline unsigned mall_poll(const unsigned* p) {
  unsigned v;
  asm volatile("global_load_dword %0, %1, off sc0 sc1\n\ts_waitcnt vmcnt(0)"
               : "=&v"(v) : "v"(p) : "memory");
  return v;
}
__device__ inline void poll2(const unsigned* p0, const unsigned* p1, unsigned& a, unsigned& b) {
  asm volatile("global_load_dword %0, %2, off sc0 sc1\n\t"
               "global_load_dword %1, %3, off sc0 sc1\n\t"
               "s_waitcnt vmcnt(0)"
               : "=&v"(a), "=&v"(b) : "v"(p0), "v"(p1) : "memory");
}
__device__ inline void gbar_wait(unsigned* fl, unsigned phase) {
  if (threadIdx.x < 64) {
    unsigned* p = fl + (size_t)(threadIdx.x & 31)*16;
    int spins = 0;
    for (;;) {
      unsigned v = mall_poll(p);
      if (__all(v >= phase)) break;
      if (((++spins) & 255) == 255) {
        unsigned a = __hip_atomic_fetch_add(p, 0u, __ATOMIC_RELAXED, __HIP_MEMORY_SCOPE_AGENT);
        if (__all(a >= phase)) break;
      }
    }
  }
  __syncthreads();
  __builtin_amdgcn_sched_barrier(0);
}
__device__ inline void ybar_wait2(unsigned* flA, unsigned* flB, unsigned phase) {
  if (threadIdx.x < 64) {
    unsigned* p0 = flA + (size_t)(threadIdx.x & 31)*16;
    unsigned* p1 = flB + (size_t)(threadIdx.x & 31)*16;
    int spins = 0;
    for (;;) {
      unsigned a, b;
      poll2(p0, p1, a, b);
      if (__all((a >= phase) && (b >= phase))) break;
      if (((++spins) & 255) == 255) {
        a = __hip_atomic_fetch_add(p0, 0u, __ATOMIC_RELAXED, __HIP_MEMORY_SCOPE_AGENT);
        b = __hip_atomic_fetch_add(p1, 0u, __ATOMIC_RELAXED, __HIP_MEMORY_SCOPE_AGENT);
        if (__all((a >= phase) && (b >= phase))) break;
      }
    }
  }
  __syncthreads();
  __builtin_amdgcn_sched_barrier(0);
}

// ======================= weight packing (fragment order) =======================
// frag elem index within a WG slice: ((mt*KT + kt)*64 + lane)*8 + e
// lane = lg*16 + ln holds row (mt*16+ln), k = kt*32 + lg*8 + e

__global__ __launch_bounds__(256) void k_pack_wc(const float* __restrict__ uW0, const float* __restrict__ lW0,
                                                 const float* __restrict__ linW, unsigned short* __restrict__ WAf) {
  int blk = blockIdx.x;                 // 2*1536 blocks
  int branch = blk / 1536, p = blk % 1536;
  const float* W0 = branch ? lW0 : uW0;
  int s = gate_src_row(p);
  int w = p / 48, rr = p % 48, mt = rr >> 4, ln = rr & 15;
  __shared__ float a[256];
  int tid = threadIdx.x;
  a[tid] = W0[(size_t)s*512 + tid];     // W0p row (cols 0:256 = prev-embed part)
  __syncthreads();
  size_t baseA = (((size_t)(branch*GW + w)*3 + mt)*24) * 64 * 8;
  for (int kk = 0; kk < 2; ++kk) {
    int k = kk*256 + tid;
    float acc = 0.f;
    #pragma unroll 8
    for (int e = 0; e < 256; ++e) acc = fmaf(a[e], linW[(size_t)e*512 + k], acc);
    int kt = k >> 5, lg = (k >> 3) & 3, e = k & 7;
    WAf[baseA + ((size_t)kt*64 + lg*16 + ln)*8 + e] = f2bf(acc);
  }
}

__global__ __launch_bounds__(256) void k_pack_rest(
    const float* __restrict__ uW0, const float* __restrict__ ubi0, const float* __restrict__ ubh0,
    const float* __restrict__ uW1, const float* __restrict__ ubi1, const float* __restrict__ ubh1,
    const float* __restrict__ lW0, const float* __restrict__ lbi0, const float* __restrict__ lbh0,
    const float* __restrict__ lW1, const float* __restrict__ lbi1, const float* __restrict__ lbh1,
    const float* __restrict__ linb,
    unsigned short* __restrict__ WAf, unsigned short* __restrict__ WBf,
    float* __restrict__ bA0, float* __restrict__ bA1, float* __restrict__ bBv) {
  int blk = blockIdx.x;
  int branch = blk / 1536, p = blk % 1536;
  const float* W0  = branch ? lW0  : uW0;
  const float* bi0 = branch ? lbi0 : ubi0;
  const float* bh0 = branch ? lbh0 : ubh0;
  const float* W1  = branch ? lW1  : uW1;
  const float* bi1 = branch ? lbi1 : ubi1;
  const float* bh1 = branch ? lbh1 : ubh1;
  int s = gate_src_row(p);
  int w = p / 48, rr = p % 48, mt = rr >> 4, ln = rr & 15;
  int tid = threadIdx.x;
  size_t baseA = (((size_t)(branch*GW + w)*3 + mt)*24) * 64 * 8;
  size_t baseB = (((size_t)(branch*GW + w)*3 + mt)*16) * 64 * 8;
  {  // W0f (feat part) -> kt 16..23
    int c = tid;
    int kt = 16 + (c >> 5), lg = (c >> 3) & 3, e = c & 7;
    WAf[baseA + ((size_t)kt*64 + lg*16 + ln)*8 + e] = f2bf(W0[(size_t)s*512 + 256 + c]);
  }
  for (int half = 0; half < 2; ++half) {
    int k = half*256 + tid;
    int kt = k >> 5, lg = (k >> 3) & 3, e = k & 7;
    WBf[baseB + ((size_t)kt*64 + lg*16 + ln)*8 + e] = f2bf(W1[(size_t)s*512 + k]);
  }
  __shared__ float red[256];
  red[tid] = W0[(size_t)s*512 + tid] * linb[tid];   // c0 = W0p @ lin_b
  __syncthreads();
  for (int st = 128; st > 0; st >>= 1) { if (tid < st) red[tid] += red[tid + st]; __syncthreads(); }
  if (tid == 0) {
    size_t rowA = (size_t)branch*1536 + p;
    float b0 = bi0[s] + bh0[s];
    bA0[rowA] = b0;
    bA1[rowA] = b0 + red[0];
    bBv[rowA] = bi1[s] + bh1[s];
  }
}

__global__ __launch_bounds__(256) void k_pack_wy(const float* __restrict__ linW, unsigned short* __restrict__ WYf) {
  int row = blockIdx.x;                 // 256 blocks
  int w2 = row >> 5, rr = row & 31, mt = rr >> 4, ln = rr & 15;
  int tid = threadIdx.x;
  size_t base = ((size_t)(w2*2 + mt)*16) * 64 * 8;
  for (int half = 0; half < 2; ++half) {
    int k = half*256 + tid;
    int kt = k >> 5, lg = (k >> 3) & 3, e = k & 7;
    WYf[base + ((size_t)kt*64 + lg*16 + ln)*8 + e] = f2bf(linW[(size_t)row*512 + k]);
  }
}

// ======================= persistent recurrent kernel =======================

__global__ __launch_bounds__(256, 1) void k_rnn(
    const float* __restrict__ featU, const float* __restrict__ featL,
    const float* __restrict__ linb,
    float* __restrict__ out, unsigned char* __restrict__ ws) {

  extern __shared__ unsigned char lds[];
  const int bid = blockIdx.x;
  const bool isGate = bid < 128;
  const int branch = isGate ? (bid >> 6) : ((bid - 128) >> 3);
  const int half   = isGate ? ((bid >> 5) & 1) : 0;
  const int w      = isGate ? (bid & 31) : ((bid - 128) & 7);
  const float* feat = branch ? featL : featU;

  const unsigned short* WAf = (const unsigned short*)(ws + OFF_WA);
  const unsigned short* WYf = (const unsigned short*)(ws + OFF_WY);
  const unsigned short* WBf = (const unsigned short*)(ws + OFF_WB);
  const float* bA0 = (const float*)(ws + OFF_BA0) + branch*1536;
  const float* bA1 = (const float*)(ws + OFF_BA1) + branch*1536;
  const float* bBv = (const float*)(ws + OFF_BBv) + branch*1536;
  unsigned short* xAr = (unsigned short*)(ws + OFF_XA);   // h1 slots [RROTA][2][...]
  unsigned short* xBr = (unsigned short*)(ws + OFF_XB);   // h0 slots [RROTB][2][...]
  unsigned* fl  = (unsigned*)(ws + (size_t)(branch*2 + half)*2048);   // own domain
  unsigned* fl0 = (unsigned*)(ws + (size_t)(branch*2 + 0)*2048);      // y: both halves
  unsigned* fl1 = (unsigned*)(ws + (size_t)(branch*2 + 1)*2048);

  const int tid = threadIdx.x;
  const int l   = tid & 63;
  const int wv  = tid >> 6;   // wave 0..3
  const int lg  = l >> 4;     // k-subgroup 0..3
  const int ln  = l & 15;     // row/col in tile

  // ---- stage weights into LDS ----
  if (isGate) {
    const uint4* srcA = (const uint4*)(WAf + (size_t)(branch*GW + w)*36864);
    uint4* dA = (uint4*)lds;
    for (int i = tid; i < 4608; i += 256) dA[i] = srcA[i];
    const uint4* srcB = (const uint4*)(WBf + (size_t)(branch*GW + w)*24576);
    uint4* dB = (uint4*)(lds + 73728);
    for (int i = tid; i < 3072; i += 256) dB[i] = srcB[i];
  } else {
    const uint4* srcY = (const uint4*)(WYf + (size_t)w*16384);
    uint4* dY = (uint4*)lds;
    for (int i = tid; i < 2048; i += 256) dY[i] = srcY[i];
  }

  // ---- per-lane bias preload ----
  float ba0[12], ba1[12], bbv[12], by[8];
  if (isGate) {
    #pragma unroll
    for (int mt = 0; mt < 3; ++mt)
      #pragma unroll
      for (int rg = 0; rg < 4; ++rg) {
        int p = 48*w + mt*16 + 4*lg + rg;
        ba0[mt*4+rg] = bA0[p];
        ba1[mt*4+rg] = bA1[p];
        bbv[mt*4+rg] = bBv[p];
      }
  } else {
    #pragma unroll
    for (int mt = 0; mt < 2; ++mt)
      #pragma unroll
      for (int rg = 0; rg < 4; ++rg)
        by[mt*4+rg] = linb[32*w + mt*16 + 4*lg + rg];
  }
  __syncthreads();

  const f32x4 zv = {0.f, 0.f, 0.f, 0.f};

  if (isGate) {
    const int n = 64*half + wv*16 + ln;   // this thread's batch column (fixed)

    // featN: pre-accumulated feat-part of stage A for the NEXT timestep
    f32x4 featN[3];
    #pragma unroll
    for (int mt = 0; mt < 3; ++mt) featN[mt] = zv;

    auto featPart = [&](int lo, int hi, int tt) {
      for (int kt2 = lo; kt2 < hi; ++kt2) {
        const float* pf = feat + ((size_t)n*T_ + tt)*E_ + kt2*32 + 8*lg;
        float4 f0 = *(const float4*)pf;
        float4 f1 = *(const float4*)(pf + 4);
        u32x4 pk;
        pk.x = pk2(f0.x, f0.y); pk.y = pk2(f0.z, f0.w);
        pk.z = pk2(f1.x, f1.y); pk.w = pk2(f1.z, f1.w);
        short8 bfr = __builtin_bit_cast(short8, pk);
        #pragma unroll
        for (int mt = 0; mt < 3; ++mt) {
          short8 afr = *(const short8*)(lds + ((mt*24 + 16 + kt2)*64 + l)*16);
          featN[mt] = __builtin_amdgcn_mfma_f32_16x16x32_bf16(
              __builtin_bit_cast(bf16x8, afr), __builtin_bit_cast(bf16x8, bfr),
              featN[mt], 0, 0, 0);
        }
      }
    };

    featPart(0, 8, 0);

    for (int t = 0; t < T_; ++t) {
      const unsigned short* xA_rd = xAr + ((size_t)((t-1) & (RROTA-1))*2 + branch)*B_*H_;
      unsigned short*       xB_wr = xBr + ((size_t)(t & (RROTB-1))*2 + branch)*B_*H_;
      const unsigned short* xB_rd = xB_wr;
      unsigned short*       xA_wr = xAr + ((size_t)(t & (RROTA-1))*2 + branch)*B_*H_;

      // ---------------- stage A: h0(t) = act(Wc@h1(t-1) + featN + bias) ----------------
      f32x4 acc[3];
      #pragma unroll
      for (int mt = 0; mt < 3; ++mt) { acc[mt] = featN[mt]; featN[mt] = zv; }

      if (t > 0) {
        gbar_wait(fl, 2u*t);                 // h1(t-1) visible
        const unsigned short* base = xA_rd + (size_t)n*32 + lg*8;
        u32x4 bs[16];                        // straight 16-load batch (64 VGPRs):
        #pragma unroll                       // issue all, counted waits at use
        for (int kt = 0; kt < 16; ++kt) bs[kt] = ld_state_b128(base + (size_t)kt*4096);
        __builtin_amdgcn_sched_barrier(0);
        #pragma unroll
        for (int kt = 0; kt < 16; ++kt) {
          #pragma unroll
          for (int mt = 0; mt < 3; ++mt) {
            short8 afr = *(const short8*)(lds + ((mt*24 + kt)*64 + l)*16);
            acc[mt] = __builtin_amdgcn_mfma_f32_16x16x32_bf16(
                __builtin_bit_cast(bf16x8, afr), __builtin_bit_cast(bf16x8, bs[kt]),
                acc[mt], 0, 0, 0);
          }
        }
      }
      {
        float bcur[12];
        #pragma unroll
        for (int q = 0; q < 12; ++q) bcur[q] = (t == 0) ? ba0[q] : ba1[q];
        unsigned long long hp[4];
        #pragma unroll
        for (int rg = 0; rg < 4; ++rg) {
          float iv = acc[0][rg] + bcur[rg];
          float gv = acc[1][rg] + bcur[4+rg];
          float ov = acc[2][rg] + bcur[8+rg];
          float c  = sigf(iv) * tanh_fast(gv);
          float h  = sigf(ov) * tanh_fast(c);
          hp[rg] = (unsigned long long)f2bf(h);
        }
        unsigned long long v = hp[0] | (hp[1] << 16) | (hp[2] << 32) | (hp[3] << 48);
        st_state_u64(xB_wr + ((size_t)(w >> 1)*128 + n)*32 + (w & 1)*16 + lg*4, v);
      }
      gbar_arrive(fl, w, 2u*t + 1);
      if (t + 1 < T_) featPart(0, 4, t + 1);   // hide barrier propagation
      gbar_wait(fl, 2u*t + 1);                 // h0(t) visible

      // ---------------- stage B: h1(t) = act(W1@h0(t) + bias) ----------------
      {
        const unsigned short* base = xB_rd + (size_t)n*32 + lg*8;
        u32x4 cs[16];
        #pragma unroll
        for (int kt = 0; kt < 16; ++kt) cs[kt] = ld_state_b128(base + (size_t)kt*4096);
        __builtin_amdgcn_sched_barrier(0);
        f32x4 accB[3];
        #pragma unroll
        for (int mt = 0; mt < 3; ++mt) accB[mt] = zv;
        #pragma unroll
        for (int kt = 0; kt < 16; ++kt) {
          #pragma unroll
          for (int mt = 0; mt < 3; ++mt) {
            short8 afr = *(const short8*)(lds + 73728 + ((mt*16 + kt)*64 + l)*16);
            accB[mt] = __builtin_amdgcn_mfma_f32_16x16x32_bf16(
                __builtin_bit_cast(bf16x8, afr), __builtin_bit_cast(bf16x8, cs[kt]),
                accB[mt], 0, 0, 0);
          }
        }
        unsigned long long hp[4];
        #pragma unroll
        for (int rg = 0; rg < 4; ++rg) {
          float iv = accB[0][rg] + bbv[rg];
          float gv = accB[1][rg] + bbv[4+rg];
          float ov = accB[2][rg] + bbv[8+rg];
          float c  = sigf(iv) * tanh_fast(gv);
          float h  = sigf(ov) * tanh_fast(c);
          hp[rg] = (unsigned long long)f2bf(h);
        }
        unsigned long long v = hp[0] | (hp[1] << 16) | (hp[2] << 32) | (hp[3] << 48);
        st_state_u64(xA_wr + ((size_t)(w >> 1)*128 + n)*32 + (w & 1)*16 + lg*4, v);
      }
      gbar_arrive(fl, w, 2u*t + 2);
      if (t + 1 < T_) featPart(4, 8, t + 1);   // hide barrier propagation
      // loop top does gbar_wait(2(t+1))
    }
  } else {
    // ==================== y WGs: decoupled consumers (full batch) ====================
    for (int t = 1; t <= T_; ++t) {
      ybar_wait2(fl0, fl1, 2u*t);            // both halves' h1(t-1) visible
      const unsigned short* xA_rd = xAr + ((size_t)((t-1) & (RROTA-1))*2 + branch)*B_*H_;
      u32x4 bs[2][16];
      #pragma unroll
      for (int nt = 0; nt < 2; ++nt) {
        const int nn = (wv*2 + nt)*16 + ln;
        const unsigned short* base = xA_rd + (size_t)nn*32 + lg*8;
        #pragma unroll
        for (int kt = 0; kt < 16; ++kt)
          bs[nt][kt] = ld_state_b128(base + (size_t)kt*4096);
      }
      f32x4 acc[2][2];
      acc[0][0]=zv; acc[0][1]=zv; acc[1][0]=zv; acc[1][1]=zv;
      #pragma unroll
      for (int kt = 0; kt < 16; ++kt) {
        #pragma unroll
        for (int mt = 0; mt < 2; ++mt) {
          short8 afr = *(const short8*)(lds + ((mt*16 + kt)*64 + l)*16);
          #pragma unroll
          for (int nt = 0; nt < 2; ++nt)
            acc[mt][nt] = __builtin_amdgcn_mfma_f32_16x16x32_bf16(
                __builtin_bit_cast(bf16x8, afr), __builtin_bit_cast(bf16x8, bs[nt][kt]),
                acc[mt][nt], 0, 0, 0);
        }
      }
      #pragma unroll
      for (int mt = 0; mt < 2; ++mt)
        #pragma unroll
        for (int nt = 0; nt < 2; ++nt) {
          const int bcol = (wv*2 + nt)*16 + ln;
          float4 o;
          o.x = acc[mt][nt][0] + by[mt*4+0];
          o.y = acc[mt][nt][1] + by[mt*4+1];
          o.z = acc[mt][nt][2] + by[mt*4+2];
          o.w = acc[mt][nt][3] + by[mt*4+3];
          *(float4*)(out + (size_t)branch*TBE_ + ((size_t)(t-1)*B_ + bcol)*E_ + 32*w + mt*16 + 4*lg) = o;
        }
    }
  }
}

// ======================= launch =======================

extern "C" void kernel_launch(void* const* d_in, const int* in_sizes, int n_in,
                              void* d_out, int out_size, void* d_ws, size_t ws_size,
                              hipStream_t stream) {
  (void)in_sizes; (void)n_in; (void)out_size; (void)ws_size;
  const float* upF  = (const float*)d_in[0];
  const float* loF  = (const float*)d_in[1];
  const float* uW0  = (const float*)d_in[2];
  const float* ubi0 = (const float*)d_in[3];
  const float* ubh0 = (const float*)d_in[4];
  const float* uW1  = (const float*)d_in[5];
  const float* ubi1 = (const float*)d_in[6];
  const float* ubh1 = (const float*)d_in[7];
  const float* lW0  = (const float*)d_in[8];
  const float* lbi0 = (const float*)d_in[9];
  const float* lbh0 = (const float*)d_in[10];
  const float* lW1  = (const float*)d_in[11];
  const float* lbi1 = (const float*)d_in[12];
  const float* lbh1 = (const float*)d_in[13];
  const float* linW = (const float*)d_in[14];
  const float* linb = (const float*)d_in[15];
  float* out = (float*)d_out;
  unsigned char* ws = (unsigned char*)d_ws;

  unsigned short* WAf = (unsigned short*)(ws + OFF_WA);
  unsigned short* WYf = (unsigned short*)(ws + OFF_WY);
  unsigned short* WBf = (unsigned short*)(ws + OFF_WB);
  float* bA0 = (float*)(ws + OFF_BA0);
  float* bA1 = (float*)(ws + OFF_BA1);
  float* bBv = (float*)(ws + OFF_BBv);

  hipMemsetAsync(d_ws, 0, 8192, stream);   // zero the 4 flag domains

  k_pack_wc<<<dim3(2*1536), dim3(256), 0, stream>>>(uW0, lW0, linW, WAf);
  k_pack_rest<<<dim3(2*1536), dim3(256), 0, stream>>>(uW0, ubi0, ubh0, uW1, ubi1, ubh1,
                                                      lW0, lbi0, lbh0, lW1, lbi1, lbh1,
                                                      linb, WAf, WBf, bA0, bA1, bBv);
  k_pack_wy<<<dim3(256), dim3(256), 0, stream>>>(linW, WYf);

  hipFuncSetAttribute((const void*)k_rnn, hipFuncAttributeMaxDynamicSharedMemorySize, LDS_BYTES);
  k_rnn<<<dim3(NWG), dim3(256), LDS_BYTES, stream>>>(upF, loF, linb, out, ws);
}